// Round 1
// baseline (5353.137 us; speedup 1.0000x reference)
//
#include <hip/hip_runtime.h>
#include <math.h>

// ---------------- problem constants ----------------
#define TT  48
#define BB_ 64
#define BC  128
#define EE  300
#define HH  300
#define G4  1200
#define D2  600
#define MR  6144   // TT*BC rows

// ---------------- workspace layout (float offsets) ----------------
#define OFF_EMB   0                          // 6144*300  (reused as h1 after encoder)
#define OFF_GF    (OFF_EMB + 6144*300)       // 6144*1200
#define OFF_GR    (OFF_GF + 6144*1200)       // 6144*1200
#define OFF_ST    (OFF_GR + 6144*1200)       // 6*38400: hf0,hr0,cf,cr,hf1,hr1
#define ST_HF0 0
#define ST_HR0 38400
#define ST_CF  76800
#define ST_CR  115200
#define ST_HF1 153600
#define ST_HR1 192000
#define OFF_CTX   (OFF_ST + 6*38400)         // 6144*600 (seq-major rows)
#define OFF_AT    (OFF_CTX + 6144*600)       // 6144*600
#define OFF_SC    (OFF_AT + 6144*600)        // 64*48*48
#define OFF_WC    (OFF_SC + 64*48*48)        // 300*1800
#define OFF_DCTX  (OFF_WC + 300*1800)        // 128*600
#define OFF_POOL  (OFF_DCTX + 128*600)       // 64*2400
#define OFF_LOGIT (OFF_POOL + 64*2400)       // 64*300

__device__ __forceinline__ float sigf(float x) { return 1.0f / (1.0f + expf(-x)); }

// ---------------- K1: embedding gather  [t][bc][300] ----------------
__global__ __launch_bounds__(256) void gather_k(const int* __restrict__ x1,
                                                const int* __restrict__ x2,
                                                const float* __restrict__ emb,
                                                float* __restrict__ out) {
    int idx = blockIdx.x * 256 + threadIdx.x;
    if (idx >= MR * EE) return;
    int r = idx / EE, e = idx % EE;
    int t = r >> 7, bc = r & 127;
    int tok = (bc < 64) ? x1[t * 64 + bc] : x2[t * 64 + bc - 64];
    out[idx] = emb[tok * EE + e];
}

// ---------------- K2: folded fc1 weight  Wc[300][1800] ----------------
__global__ __launch_bounds__(256) void wcat_k(const float* __restrict__ f1w,
                                              float* __restrict__ wc) {
    int idx = blockIdx.x * 256 + threadIdx.x;
    if (idx >= 300 * 1800) return;
    int n = idx / 1800, k = idx % 1800;
    int nk = n * 2400 + k;
    float v;
    if (k < 600)       v = f1w[nk] + f1w[nk + 1800];   // c coeff: W1+W4
    else if (k < 1200) v = f1w[nk] - f1w[nk + 1200];   // a coeff: W2-W4
    else               v = f1w[nk];                    // c*a coeff: W3
    wc[idx] = v;
}

// ---------------- generic fp32 GEMM: C[M,N] = A[M,K] * W[N,K]^T + b1 + b2 ----------------
__global__ __launch_bounds__(256) void gemm_nt(const float* __restrict__ A,
                                               const float* __restrict__ W,
                                               const float* __restrict__ bias1,
                                               const float* __restrict__ bias2,
                                               float* __restrict__ C,
                                               int M, int N, int K) {
    __shared__ float As[16][64];
    __shared__ float Ws[16][64];
    int m0 = blockIdx.x * 64, n0 = blockIdx.y * 64;
    int tid = threadIdx.x;
    int lrow = tid >> 2;            // 0..63
    int lk4  = (tid & 3) << 2;      // 0,4,8,12
    int tm = (tid & 15) << 2;
    int tn = (tid >> 4) << 2;
    int nW = n0 + lrow;
    float acc[4][4] = {};
    for (int k0 = 0; k0 < K; k0 += 16) {
        __syncthreads();
#pragma unroll
        for (int q = 0; q < 4; q++) {
            int k = k0 + lk4 + q;
            As[lk4 + q][lrow] = (k < K) ? A[(m0 + lrow) * K + k] : 0.0f;
            Ws[lk4 + q][lrow] = (k < K && nW < N) ? W[nW * K + k] : 0.0f;
        }
        __syncthreads();
#pragma unroll
        for (int kk = 0; kk < 16; kk++) {
            float a0 = As[kk][tm], a1 = As[kk][tm + 1], a2 = As[kk][tm + 2], a3 = As[kk][tm + 3];
            float w0 = Ws[kk][tn], w1 = Ws[kk][tn + 1], w2 = Ws[kk][tn + 2], w3 = Ws[kk][tn + 3];
            acc[0][0] += a0 * w0; acc[0][1] += a0 * w1; acc[0][2] += a0 * w2; acc[0][3] += a0 * w3;
            acc[1][0] += a1 * w0; acc[1][1] += a1 * w1; acc[1][2] += a1 * w2; acc[1][3] += a1 * w3;
            acc[2][0] += a2 * w0; acc[2][1] += a2 * w1; acc[2][2] += a2 * w2; acc[2][3] += a2 * w3;
            acc[3][0] += a3 * w0; acc[3][1] += a3 * w1; acc[3][2] += a3 * w2; acc[3][3] += a3 * w3;
        }
    }
#pragma unroll
    for (int ii = 0; ii < 4; ii++) {
        int m = m0 + tm + ii;  // M is always a multiple of 64 here
#pragma unroll
        for (int jn = 0; jn < 4; jn++) {
            int n = n0 + tn + jn;
            if (n < N) {
                float v = acc[ii][jn] + bias1[n] + (bias2 ? bias2[n] : 0.0f);
                C[m * N + n] = v;
            }
        }
    }
}

// ---------------- fc1 GEMM: virtual A = [ctx | at | ctx*at], relu, t-major remap ----------------
__global__ __launch_bounds__(256) void gemm_fc1(const float* __restrict__ ctx,
                                                const float* __restrict__ at,
                                                const float* __restrict__ Wc,
                                                const float* __restrict__ bias,
                                                float* __restrict__ Cout) {
    __shared__ float As[16][64];
    __shared__ float Ws[16][64];
    const int K = 1800, N = 300;
    int m0 = blockIdx.x * 64, n0 = blockIdx.y * 64;
    int tid = threadIdx.x;
    int lrow = tid >> 2;
    int lk4  = (tid & 3) << 2;
    int tm = (tid & 15) << 2;
    int tn = (tid >> 4) << 2;
    int nW = n0 + lrow;
    int mA = m0 + lrow;
    float acc[4][4] = {};
    for (int k0 = 0; k0 < K; k0 += 16) {
        __syncthreads();
#pragma unroll
        for (int q = 0; q < 4; q++) {
            int k = k0 + lk4 + q;
            float av = 0.0f;
            if (k < 600)       av = ctx[mA * 600 + k];
            else if (k < 1200) av = at[mA * 600 + k - 600];
            else if (k < 1800) { int k2 = k - 1200; av = ctx[mA * 600 + k2] * at[mA * 600 + k2]; }
            As[lk4 + q][lrow] = av;
            Ws[lk4 + q][lrow] = (k < K && nW < N) ? Wc[nW * K + k] : 0.0f;
        }
        __syncthreads();
#pragma unroll
        for (int kk = 0; kk < 16; kk++) {
            float a0 = As[kk][tm], a1 = As[kk][tm + 1], a2 = As[kk][tm + 2], a3 = As[kk][tm + 3];
            float w0 = Ws[kk][tn], w1 = Ws[kk][tn + 1], w2 = Ws[kk][tn + 2], w3 = Ws[kk][tn + 3];
            acc[0][0] += a0 * w0; acc[0][1] += a0 * w1; acc[0][2] += a0 * w2; acc[0][3] += a0 * w3;
            acc[1][0] += a1 * w0; acc[1][1] += a1 * w1; acc[1][2] += a1 * w2; acc[1][3] += a1 * w3;
            acc[2][0] += a2 * w0; acc[2][1] += a2 * w1; acc[2][2] += a2 * w2; acc[2][3] += a2 * w3;
            acc[3][0] += a3 * w0; acc[3][1] += a3 * w1; acc[3][2] += a3 * w2; acc[3][3] += a3 * w3;
        }
    }
#pragma unroll
    for (int ii = 0; ii < 4; ii++) {
        int m = m0 + tm + ii;                    // seq-major row
        int seq = m / 3072, rem = m % 3072;
        int t = rem / 64, b = rem & 63;
        int orow = t * 128 + seq * 64 + b;       // t-major row for decoder input
#pragma unroll
        for (int jn = 0; jn < 4; jn++) {
            int n = n0 + tn + jn;
            if (n < N) {
                float v = acc[ii][jn] + bias[n];
                Cout[orow * 300 + n] = fmaxf(v, 0.0f);
            }
        }
    }
}

// ---------------- fused LSTM step: h@U^T + G, gates, both directions ----------------
// grid (19 j-tiles of 16, 4 b-tiles of 32, 2 dirs), block 256
__global__ __launch_bounds__(256) void lstm_step(const float* __restrict__ Gf,
                                                 const float* __restrict__ Gr,
                                                 const float* __restrict__ Uf,
                                                 const float* __restrict__ Ur,
                                                 const float* __restrict__ hinF,
                                                 float* __restrict__ houtF,
                                                 const float* __restrict__ hinR,
                                                 float* __restrict__ houtR,
                                                 float* __restrict__ cF,
                                                 float* __restrict__ cR,
                                                 int t) {
    int dir = blockIdx.z;
    const float* G = dir ? Gr : Gf;
    const float* U = dir ? Ur : Uf;
    const float* hin = dir ? hinR : hinF;
    float* hout = dir ? houtR : houtF;
    float* c = dir ? cR : cF;
    int tt = dir ? (47 - t) : t;

    int j0 = blockIdx.x * 16;
    int b0 = blockIdx.y * 32;
    int tid = threadIdx.x;
    int col = tid & 63;            // 0..63 = 4 gates x 16 j
    int bg  = tid >> 6;            // 0..3
    int gate = col >> 4, jl = col & 15;
    int j = j0 + jl;
    int urow = gate * 300 + j;

    __shared__ float Us[64][33];
    __shared__ float Hs[32][33];
    __shared__ float P[32][65];

    int kk8 = (tid >> 6) * 8;
    int bi = tid & 31, kk4 = (tid >> 5) * 4;
    float acc[8] = {};

    for (int k0 = 0; k0 < 300; k0 += 32) {
        __syncthreads();
#pragma unroll
        for (int q = 0; q < 8; q++) {
            int k = k0 + kk8 + q;
            Us[col][kk8 + q] = (j < 300 && k < 300) ? U[urow * 300 + k] : 0.0f;
        }
#pragma unroll
        for (int q = 0; q < 4; q++) {
            int k = k0 + kk4 + q;
            Hs[bi][kk4 + q] = (k < 300) ? hin[(b0 + bi) * 300 + k] : 0.0f;
        }
        __syncthreads();
#pragma unroll
        for (int kk = 0; kk < 32; kk++) {
            float u = Us[col][kk];
#pragma unroll
            for (int i = 0; i < 8; i++)
                acc[i] += u * Hs[bg * 8 + i][kk];
        }
    }
#pragma unroll
    for (int i = 0; i < 8; i++) {
        int bA = b0 + bg * 8 + i;
        float p = acc[i];
        if (j < 300) p += G[(tt * 128 + bA) * 1200 + urow];
        P[bg * 8 + i][col] = p;
    }
    __syncthreads();
#pragma unroll
    for (int ii = 0; ii < 2; ii++) {
        int p = tid + 256 * ii;     // 0..511 = 32 b x 16 j
        int bl = p >> 4, j2 = p & 15;
        int jj = j0 + j2;
        if (jj < 300) {
            float gi = P[bl][j2], gf = P[bl][16 + j2], gg = P[bl][32 + j2], go = P[bl][48 + j2];
            int ci = (b0 + bl) * 300 + jj;
            float cn = sigf(gf) * c[ci] + sigf(gi) * tanhf(gg);
            float hn = sigf(go) * tanhf(cn);
            c[ci] = cn;
            hout[ci] = hn;
        }
    }
}

// ---------------- encoder context build: ctx[r][d] (seq-major rows, masked) ----------------
__global__ __launch_bounds__(256) void ctx_k(const float* __restrict__ hF,
                                             const float* __restrict__ hR,
                                             const float* __restrict__ x1m,
                                             const float* __restrict__ x2m,
                                             float* __restrict__ ctx) {
    int idx = blockIdx.x * 256 + threadIdx.x;
    if (idx >= MR * D2) return;
    int r = idx / D2, d = idx % D2;
    int seq = r / 3072, rem = r % 3072;
    int t = rem / 64, b = rem & 63;
    int bc = seq * 64 + b;
    float v = (d < 300) ? hF[bc * 300 + d] : hR[(seq * 64 + 63 - b) * 300 + d - 300];
    float mk = seq ? x2m[t * 64 + b] : x1m[t * 64 + b];
    ctx[idx] = v * mk;
}

// ---------------- scores[b][i][j] = max_d c1[b,i,d]*c2[b,j,d] ----------------
__global__ __launch_bounds__(256) void scores_k(const float* __restrict__ ctx,
                                                float* __restrict__ sc) {
    int i = blockIdx.x, b = blockIdx.y;
    __shared__ float c1s[600];
    __shared__ float c2s[48][121];
    int tid = threadIdx.x;
    for (int d = tid; d < 600; d += 256) c1s[d] = ctx[(i * 64 + b) * 600 + d];
    float m = -3.4e38f;
    for (int d0 = 0; d0 < 600; d0 += 120) {
        __syncthreads();
        for (int q = tid; q < 48 * 120; q += 256) {
            int j = q / 120, dd = q % 120;
            c2s[j][dd] = ctx[(3072 + j * 64 + b) * 600 + d0 + dd];
        }
        __syncthreads();
        if (tid < 48) {
            for (int dd = 0; dd < 120; dd++)
                m = fmaxf(m, c1s[d0 + dd] * c2s[tid][dd]);
        }
    }
    if (tid < 48) sc[(b * 48 + i) * 48 + tid] = m;
}

// ---------------- alpha softmax (axis j) + a_tilde = max_j alpha*c2 ----------------
__global__ __launch_bounds__(256) void att_a(const float* __restrict__ sc,
                                             const float* __restrict__ ctx,
                                             const float* __restrict__ x2m,
                                             float* __restrict__ at) {
    int i = blockIdx.x, b = blockIdx.y;
    __shared__ float alpha[48];
    __shared__ float red;
    __shared__ float c2s[48][121];
    int tid = threadIdx.x;
    if (tid < 48) alpha[tid] = sc[(b * 48 + i) * 48 + tid];
    __syncthreads();
    if (tid == 0) {
        float mx = alpha[0];
        for (int j = 1; j < 48; j++) mx = fmaxf(mx, alpha[j]);
        red = mx;
    }
    __syncthreads();
    if (tid < 48) alpha[tid] = expf(alpha[tid] - red) * x2m[tid * 64 + b];
    __syncthreads();
    if (tid == 0) {
        float s = 0;
        for (int j = 0; j < 48; j++) s += alpha[j];
        red = s;
    }
    __syncthreads();
    if (tid < 48) alpha[tid] /= red;
    for (int d0 = 0; d0 < 600; d0 += 120) {
        __syncthreads();
        for (int q = tid; q < 48 * 120; q += 256) {
            int j = q / 120, dd = q % 120;
            c2s[j][dd] = ctx[(3072 + j * 64 + b) * 600 + d0 + dd];
        }
        __syncthreads();
        if (tid < 120) {
            float m = -3.4e38f;
#pragma unroll
            for (int j = 0; j < 48; j++) m = fmaxf(m, alpha[j] * c2s[j][tid]);
            at[(i * 64 + b) * 600 + d0 + tid] = m;
        }
    }
}

// ---------------- beta softmax (axis i) + b_tilde = sum_i beta*c1 ----------------
__global__ __launch_bounds__(256) void att_b(const float* __restrict__ sc,
                                             const float* __restrict__ ctx,
                                             const float* __restrict__ x1m,
                                             float* __restrict__ at) {
    int jj = blockIdx.x, b = blockIdx.y;
    __shared__ float beta[48];
    __shared__ float red;
    __shared__ float c1s[48][121];
    int tid = threadIdx.x;
    if (tid < 48) beta[tid] = sc[(b * 48 + tid) * 48 + jj];
    __syncthreads();
    if (tid == 0) {
        float mx = beta[0];
        for (int i2 = 1; i2 < 48; i2++) mx = fmaxf(mx, beta[i2]);
        red = mx;
    }
    __syncthreads();
    if (tid < 48) beta[tid] = expf(beta[tid] - red) * x1m[tid * 64 + b];
    __syncthreads();
    if (tid == 0) {
        float s = 0;
        for (int i2 = 0; i2 < 48; i2++) s += beta[i2];
        red = s;
    }
    __syncthreads();
    if (tid < 48) beta[tid] /= red;
    for (int d0 = 0; d0 < 600; d0 += 120) {
        __syncthreads();
        for (int q = tid; q < 48 * 120; q += 256) {
            int i2 = q / 120, dd = q % 120;
            c1s[i2][dd] = ctx[(i2 * 64 + b) * 600 + d0 + dd];
        }
        __syncthreads();
        if (tid < 120) {
            float s = 0;
#pragma unroll
            for (int i2 = 0; i2 < 48; i2++) s += beta[i2] * c1s[i2][tid];
            at[(3072 + jj * 64 + b) * 600 + d0 + tid] = s;
        }
    }
}

// ---------------- decoder context build (quirk: batch-reversed reverse hidden) ----------------
__global__ __launch_bounds__(256) void dctx_k(const float* __restrict__ hF,
                                              const float* __restrict__ hR,
                                              float* __restrict__ dctx) {
    int idx = blockIdx.x * 256 + threadIdx.x;
    if (idx >= 128 * 600) return;
    int bc = idx / 600, d = idx % 600;
    int seq = bc >> 6, b = bc & 63;
    dctx[idx] = (d < 300) ? hF[bc * 300 + d] : hR[(seq * 64 + 63 - b) * 300 + d - 300];
}

// ---------------- masked mean/max pooling -> pooled[64][2400] ----------------
__global__ __launch_bounds__(256) void pool_k(const float* __restrict__ dctx,
                                              const float* __restrict__ x1m,
                                              const float* __restrict__ x2m,
                                              float* __restrict__ pooled) {
    int idx = blockIdx.x * 256 + threadIdx.x;
    if (idx >= 64 * 2400) return;
    int b = idx / 2400, col = idx % 2400;
    int sec = col / 600, d = col % 600;
    const float* msk = (sec < 2) ? x1m : x2m;
    float v = dctx[((sec < 2 ? 0 : 64) + b) * 600 + d];
    float out;
    if ((sec & 1) == 0) {
        float s = 0, sm = 0;
        for (int t = 0; t < 48; t++) { float mv = msk[t * 64 + b]; s += v * mv; sm += mv; }
        out = s / sm;
    } else {
        float m = -3.4e38f;
        for (int t = 0; t < 48; t++) m = fmaxf(m, v * msk[t * 64 + b]);
        out = m;
    }
    pooled[idx] = out;
}

// ---------------- fc2 + tanh: logit[64][300] ----------------
__global__ __launch_bounds__(256) void fc2_k(const float* __restrict__ pooled,
                                             const float* __restrict__ f2w,
                                             const float* __restrict__ f2b,
                                             float* __restrict__ logit) {
    __shared__ float ps[64][33];
    int tid = threadIdx.x;
    int b = tid & 63, nl = tid >> 6;
    int n = blockIdx.x * 4 + nl;
    int lrow = tid >> 2, lk = (tid & 3) << 3;
    float acc = 0;
    for (int k0 = 0; k0 < 2400; k0 += 32) {
        __syncthreads();
#pragma unroll
        for (int q = 0; q < 8; q++)
            ps[lrow][lk + q] = pooled[lrow * 2400 + k0 + lk + q];
        __syncthreads();
#pragma unroll
        for (int kk = 0; kk < 32; kk++)
            acc += ps[b][kk] * f2w[n * 2400 + k0 + kk];
    }
    logit[b * 300 + n] = tanhf(acc + f2b[n]);
}

// ---------------- output layer: out[64][3] ----------------
__global__ __launch_bounds__(256) void out_k(const float* __restrict__ logit,
                                             const float* __restrict__ fow,
                                             const float* __restrict__ fob,
                                             float* __restrict__ out) {
    int tid = threadIdx.x;
    if (tid < 192) {
        int b = tid / 3, o = tid % 3;
        float acc = fob[o];
        for (int k = 0; k < 300; k++) acc += logit[b * 300 + k] * fow[o * 300 + k];
        out[tid] = acc;
    }
}

extern "C" void kernel_launch(void* const* d_in, const int* in_sizes, int n_in,
                              void* d_out, int out_size, void* d_ws, size_t ws_size,
                              hipStream_t stream) {
    (void)in_sizes; (void)n_in; (void)out_size; (void)ws_size;
    const int*   x1  = (const int*)d_in[0];
    const float* x1m = (const float*)d_in[1];
    const int*   x2  = (const int*)d_in[2];
    const float* x2m = (const float*)d_in[3];
    // d_in[4] = l (unused)
    const float* emb = (const float*)d_in[5];
    const float* eW  = (const float*)d_in[6];
    const float* eU  = (const float*)d_in[7];
    const float* ebi = (const float*)d_in[8];
    const float* ebh = (const float*)d_in[9];
    const float* rW  = (const float*)d_in[10];
    const float* rU  = (const float*)d_in[11];
    const float* rbi = (const float*)d_in[12];
    const float* rbh = (const float*)d_in[13];
    const float* dW  = (const float*)d_in[14];
    const float* dU  = (const float*)d_in[15];
    const float* dbi = (const float*)d_in[16];
    const float* dbh = (const float*)d_in[17];
    const float* sW  = (const float*)d_in[18];
    const float* sU  = (const float*)d_in[19];
    const float* sbi = (const float*)d_in[20];
    const float* sbh = (const float*)d_in[21];
    const float* f1w = (const float*)d_in[22];
    const float* f1b = (const float*)d_in[23];
    const float* f2w = (const float*)d_in[24];
    const float* f2b = (const float*)d_in[25];
    const float* fow = (const float*)d_in[26];
    const float* fob = (const float*)d_in[27];

    float* ws = (float*)d_ws;
    float* EMB = ws + OFF_EMB;          // embeddings, later h1
    float* GF  = ws + OFF_GF;
    float* GR  = ws + OFF_GR;
    float* HF0 = ws + OFF_ST + ST_HF0;
    float* HR0 = ws + OFF_ST + ST_HR0;
    float* CF  = ws + OFF_ST + ST_CF;
    float* CR  = ws + OFF_ST + ST_CR;
    float* HF1 = ws + OFF_ST + ST_HF1;
    float* HR1 = ws + OFF_ST + ST_HR1;
    float* CTX = ws + OFF_CTX;
    float* AT  = ws + OFF_AT;
    float* SC  = ws + OFF_SC;
    float* WC  = ws + OFF_WC;
    float* DCTX = ws + OFF_DCTX;
    float* POOL = ws + OFF_POOL;
    float* LOGIT = ws + OFF_LOGIT;

    // embedding gather + folded fc1 weights
    gather_k<<<dim3((MR * EE + 255) / 256), 256, 0, stream>>>(x1, x2, emb, EMB);
    wcat_k<<<dim3((300 * 1800 + 255) / 256), 256, 0, stream>>>(f1w, WC);

    // zero h0/c0 (hf0, hr0, cf, cr contiguous)
    hipMemsetAsync(ws + OFF_ST, 0, 4 * 38400 * sizeof(float), stream);

    // encoder input projections (both dirs)
    gemm_nt<<<dim3(96, 19), 256, 0, stream>>>(EMB, eW, ebi, ebh, GF, MR, 1200, 300);
    gemm_nt<<<dim3(96, 19), 256, 0, stream>>>(EMB, rW, rbi, rbh, GR, MR, 1200, 300);

    // encoder recurrence
    for (int t = 0; t < 48; t++) {
        const float* hinF = (t & 1) ? HF1 : HF0;
        float*       houtF = (t & 1) ? HF0 : HF1;
        const float* hinR = (t & 1) ? HR1 : HR0;
        float*       houtR = (t & 1) ? HR0 : HR1;
        lstm_step<<<dim3(19, 4, 2), 256, 0, stream>>>(GF, GR, eU, rU, hinF, houtF, hinR, houtR, CF, CR, t);
    }

    // masked broadcast contexts (final h in HF0/HR0 after 48 steps)
    ctx_k<<<dim3((MR * D2 + 255) / 256), 256, 0, stream>>>(HF0, HR0, x1m, x2m, CTX);

    // attention
    scores_k<<<dim3(48, 64), 256, 0, stream>>>(CTX, SC);
    att_a<<<dim3(48, 64), 256, 0, stream>>>(SC, CTX, x2m, AT);
    att_b<<<dim3(48, 64), 256, 0, stream>>>(SC, CTX, x1m, AT);

    // fc1 (virtual concat, folded weights, relu, t-major output into EMB)
    gemm_fc1<<<dim3(96, 5), 256, 0, stream>>>(CTX, AT, WC, f1b, EMB);

    // decoder phase
    hipMemsetAsync(ws + OFF_ST, 0, 4 * 38400 * sizeof(float), stream);
    gemm_nt<<<dim3(96, 19), 256, 0, stream>>>(EMB, dW, dbi, dbh, GF, MR, 1200, 300);
    gemm_nt<<<dim3(96, 19), 256, 0, stream>>>(EMB, sW, sbi, sbh, GR, MR, 1200, 300);
    for (int t = 0; t < 48; t++) {
        const float* hinF = (t & 1) ? HF1 : HF0;
        float*       houtF = (t & 1) ? HF0 : HF1;
        const float* hinR = (t & 1) ? HR1 : HR0;
        float*       houtR = (t & 1) ? HR0 : HR1;
        lstm_step<<<dim3(19, 4, 2), 256, 0, stream>>>(GF, GR, dU, sU, hinF, houtF, hinR, houtR, CF, CR, t);
    }

    // decoder contexts + pooling + classifier
    dctx_k<<<dim3((128 * 600 + 255) / 256), 256, 0, stream>>>(HF0, HR0, DCTX);
    pool_k<<<dim3((64 * 2400 + 255) / 256), 256, 0, stream>>>(DCTX, x1m, x2m, POOL);
    fc2_k<<<dim3(75), 256, 0, stream>>>(POOL, f2w, f2b, LOGIT);
    out_k<<<dim3(1), 256, 0, stream>>>(LOGIT, fow, fob, (float*)d_out);
}

// Round 2
// 4564.553 us; speedup vs baseline: 1.1728x; 1.1728x over previous
//
#include <hip/hip_runtime.h>
#include <math.h>

typedef unsigned short u16;
typedef __attribute__((ext_vector_type(8))) __bf16 bf16x8;
typedef __attribute__((ext_vector_type(4))) float f32x4;

// ---------------- problem constants ----------------
#define MR   6144      // 48*128 rows (t-major: row = t*128 + bc)
#define KP1  320       // padded K for E=H=300
#define NP1  1280      // padded N for 4H=1200
#define KP2  1824      // padded K for 3*600=1800 (fc1 folded)
#define NP2  384       // padded N for H=300 (fc1)

// ---------------- workspace layout (byte offsets, all 16B-aligned) ----------------
#define OFF_ABF    0UL           // bf16 [6144][320]            3,932,160
#define OFF_WBF    3932160UL     // bf16 4 x [1280][320]        3,276,800
#define OFF_WCBF   7208960UL     // bf16 [384][1824]            1,400,832
#define OFF_GF     8609792UL     // f32  [6144][1200]          29,491,200  (aliased by ACAT bf16 [6144][1824])
#define OFF_GR     38100992UL    // f32  [6144][1200]          29,491,200
#define OFF_ST     67592192UL    // f32  6 x 38400                921,600
#define OFF_CTX    68513792UL    // f32  [6144][600]           14,745,600
#define OFF_AT     83259392UL    // f32  [6144][600]           14,745,600
#define OFF_SC     98004992UL    // f32  64*48*48                 589,824
#define OFF_DCTX   98594816UL    // f32  128*600                  307,200
#define OFF_POOL   98902016UL    // f32  64*2400                  614,400
#define OFF_LOGIT  99516416UL    // f32  64*300                    76,800

__device__ __forceinline__ float sigf(float x) { return 1.0f / (1.0f + expf(-x)); }

__device__ __forceinline__ u16 f2bf(float x) {
    union { float f; unsigned int u; } v; v.f = x;
    unsigned int r = v.u + 0x7fffu + ((v.u >> 16) & 1u);   // RNE
    return (u16)(r >> 16);
}

__device__ __forceinline__ void gld_lds16(const u16* g, u16* l) {
    __builtin_amdgcn_global_load_lds(
        (const __attribute__((address_space(1))) unsigned int*)g,
        (__attribute__((address_space(3))) unsigned int*)l, 16, 0, 0);
}

// ---------------- embedding gather -> bf16, K zero-padded ----------------
__global__ __launch_bounds__(256) void gather_bf(const int* __restrict__ x1,
                                                 const int* __restrict__ x2,
                                                 const float* __restrict__ emb,
                                                 u16* __restrict__ abf) {
    int idx = blockIdx.x * 256 + threadIdx.x;
    if (idx >= MR * KP1) return;
    int r = idx / KP1, k = idx % KP1;
    float v = 0.0f;
    if (k < 300) {
        int t = r >> 7, bc = r & 127;
        int tok = (bc < 64) ? x1[t * 64 + bc] : x2[t * 64 + bc - 64];
        v = emb[tok * 300 + k];
    }
    abf[idx] = f2bf(v);
}

// ---------------- input-proj weights fp32 [1200][300] -> bf16 [1280][320] x4 ----------------
__global__ __launch_bounds__(256) void wconv_k(const float* __restrict__ w0,
                                               const float* __restrict__ w1,
                                               const float* __restrict__ w2,
                                               const float* __restrict__ w3,
                                               u16* __restrict__ out) {
    int idx = blockIdx.x * 256 + threadIdx.x;
    if (idx >= 4 * NP1 * KP1) return;
    int s = idx / (NP1 * KP1), rem = idx % (NP1 * KP1);
    int r = rem / KP1, k = rem % KP1;
    const float* w = (s == 0) ? w0 : (s == 1) ? w1 : (s == 2) ? w2 : w3;
    float v = (r < 1200 && k < 300) ? w[r * 300 + k] : 0.0f;
    out[idx] = f2bf(v);
}

// ---------------- folded fc1 weight -> bf16 [384][1824] ----------------
__global__ __launch_bounds__(256) void wcat_bf(const float* __restrict__ f1w,
                                               u16* __restrict__ wc) {
    int idx = blockIdx.x * 256 + threadIdx.x;
    if (idx >= NP2 * KP2) return;
    int n = idx / KP2, k = idx % KP2;
    float v = 0.0f;
    if (n < 300 && k < 1800) {
        int nk = n * 2400 + k;
        if (k < 600)       v = f1w[nk] + f1w[nk + 1800];   // c coeff: W1+W4
        else if (k < 1200) v = f1w[nk] - f1w[nk + 1200];   // a coeff: W2-W4
        else               v = f1w[nk];                    // c*a coeff: W3
    }
    wc[idx] = f2bf(v);
}

// ---------------- bf16 MFMA GEMM (m97 structure): C[M][N] f32 = A@B^T + b1 + b2 ----------------
// A [M][Kpad] bf16, B [Npad][Kpad] bf16, grid (M/128, Npad/128), block 256
__global__ __launch_bounds__(256) void gemm_bt(const u16* __restrict__ A,
                                               const u16* __restrict__ B,
                                               const float* __restrict__ b1,
                                               const float* __restrict__ b2,
                                               float* __restrict__ C,
                                               int N, int Kpad) {
    __shared__ __align__(16) u16 smA[128 * 32];
    __shared__ __align__(16) u16 smB[128 * 32];
    int m0 = blockIdx.x * 128, n0 = blockIdx.y * 128;
    int tid = threadIdx.x, ln = tid & 63;
    int wm = (tid >> 6) & 1, wn = tid >> 7;
    int lrow = ln & 15, lq = ln >> 4;
    f32x4 acc[4][4] = {};
    for (int k0 = 0; k0 < Kpad; k0 += 32) {
#pragma unroll
        for (int p = 0; p < 2; p++) {
            int e = (p * 256 + tid) * 8;       // element offset in [128][32] tile
            int r = e >> 5, kk = e & 31;
            gld_lds16(A + (size_t)(m0 + r) * Kpad + k0 + kk, smA + e);
            gld_lds16(B + (size_t)(n0 + r) * Kpad + k0 + kk, smB + e);
        }
        __syncthreads();
        bf16x8 av[4], bv[4];
#pragma unroll
        for (int i = 0; i < 4; i++) {
            av[i] = *(const bf16x8*)&smA[(wm * 64 + i * 16 + lrow) * 32 + lq * 8];
            bv[i] = *(const bf16x8*)&smB[(wn * 64 + i * 16 + lrow) * 32 + lq * 8];
        }
#pragma unroll
        for (int i = 0; i < 4; i++)
#pragma unroll
            for (int j = 0; j < 4; j++)
                acc[i][j] = __builtin_amdgcn_mfma_f32_16x16x32_bf16(av[i], bv[j], acc[i][j], 0, 0, 0);
        __syncthreads();
    }
#pragma unroll
    for (int i = 0; i < 4; i++)
#pragma unroll
        for (int j = 0; j < 4; j++) {
            int n = n0 + wn * 64 + j * 16 + lrow;
            if (n < N) {
                float bb = b1[n] + b2[n];
#pragma unroll
                for (int r = 0; r < 4; r++) {
                    int m = m0 + wm * 64 + i * 16 + lq * 4 + r;
                    C[(size_t)m * N + n] = acc[i][j][r] + bb;
                }
            }
        }
}

// ---------------- fc1 MFMA GEMM: relu(A@Wc^T + b) -> bf16 t-major [6144][320] ----------------
__global__ __launch_bounds__(256) void gemm_fc1_bt(const u16* __restrict__ A,
                                                   const u16* __restrict__ B,
                                                   const float* __restrict__ bias,
                                                   u16* __restrict__ OUT) {
    __shared__ __align__(16) u16 smA[128 * 32];
    __shared__ __align__(16) u16 smB[128 * 32];
    const int Kpad = KP2;
    int m0 = blockIdx.x * 128, n0 = blockIdx.y * 128;
    int tid = threadIdx.x, ln = tid & 63;
    int wm = (tid >> 6) & 1, wn = tid >> 7;
    int lrow = ln & 15, lq = ln >> 4;
    f32x4 acc[4][4] = {};
    for (int k0 = 0; k0 < Kpad; k0 += 32) {
#pragma unroll
        for (int p = 0; p < 2; p++) {
            int e = (p * 256 + tid) * 8;
            int r = e >> 5, kk = e & 31;
            gld_lds16(A + (size_t)(m0 + r) * Kpad + k0 + kk, smA + e);
            gld_lds16(B + (size_t)(n0 + r) * Kpad + k0 + kk, smB + e);
        }
        __syncthreads();
        bf16x8 av[4], bv[4];
#pragma unroll
        for (int i = 0; i < 4; i++) {
            av[i] = *(const bf16x8*)&smA[(wm * 64 + i * 16 + lrow) * 32 + lq * 8];
            bv[i] = *(const bf16x8*)&smB[(wn * 64 + i * 16 + lrow) * 32 + lq * 8];
        }
#pragma unroll
        for (int i = 0; i < 4; i++)
#pragma unroll
            for (int j = 0; j < 4; j++)
                acc[i][j] = __builtin_amdgcn_mfma_f32_16x16x32_bf16(av[i], bv[j], acc[i][j], 0, 0, 0);
        __syncthreads();
    }
#pragma unroll
    for (int i = 0; i < 4; i++)
#pragma unroll
        for (int j = 0; j < 4; j++) {
            int n = n0 + wn * 64 + j * 16 + lrow;
            if (n < 300) {
                float bb = bias[n];
#pragma unroll
                for (int r = 0; r < 4; r++) {
                    int m = m0 + wm * 64 + i * 16 + lq * 4 + r;     // seq-major row
                    int seq = m / 3072, rem = m % 3072;
                    int t = rem / 64, bidx = rem & 63;
                    int orow = t * 128 + seq * 64 + bidx;           // t-major for decoder
                    float v = fmaxf(acc[i][j][r] + bb, 0.0f);
                    OUT[(size_t)orow * KP1 + n] = f2bf(v);
                }
            }
        }
}

// ---------------- build fc1 A = [ctx | at | ctx*at] bf16, K zero-padded ----------------
__global__ __launch_bounds__(256) void acat_k(const float* __restrict__ ctx,
                                              const float* __restrict__ at,
                                              u16* __restrict__ acat) {
    int idx = blockIdx.x * 256 + threadIdx.x;
    if (idx >= MR * KP2) return;
    int r = idx / KP2, k = idx % KP2;
    float v = 0.0f;
    if (k < 600)        v = ctx[r * 600 + k];
    else if (k < 1200)  v = at[r * 600 + k - 600];
    else if (k < 1800) { int k2 = k - 1200; v = ctx[r * 600 + k2] * at[r * 600 + k2]; }
    acat[idx] = f2bf(v);
}

// ---------------- fused LSTM step (fp32): h@U^T + G, gates, both directions ----------------
__global__ __launch_bounds__(256) void lstm_step(const float* __restrict__ Gf,
                                                 const float* __restrict__ Gr,
                                                 const float* __restrict__ Uf,
                                                 const float* __restrict__ Ur,
                                                 const float* __restrict__ hinF,
                                                 float* __restrict__ houtF,
                                                 const float* __restrict__ hinR,
                                                 float* __restrict__ houtR,
                                                 float* __restrict__ cF,
                                                 float* __restrict__ cR,
                                                 int t) {
    int dir = blockIdx.z;
    const float* G = dir ? Gr : Gf;
    const float* U = dir ? Ur : Uf;
    const float* hin = dir ? hinR : hinF;
    float* hout = dir ? houtR : houtF;
    float* c = dir ? cR : cF;
    int tt = dir ? (47 - t) : t;

    int j0 = blockIdx.x * 16;
    int b0 = blockIdx.y * 32;
    int tid = threadIdx.x;
    int col = tid & 63;            // 4 gates x 16 j
    int bg  = tid >> 6;
    int gate = col >> 4, jl = col & 15;
    int j = j0 + jl;
    int urow = gate * 300 + j;

    __shared__ float Us[64][33];
    __shared__ float Hs[32][33];
    __shared__ float P[32][65];

    int kk8 = (tid >> 6) * 8;
    int bi = tid & 31, kk4 = (tid >> 5) * 4;
    float acc[8] = {};

    for (int k0 = 0; k0 < 300; k0 += 32) {
        __syncthreads();
#pragma unroll
        for (int q = 0; q < 8; q++) {
            int k = k0 + kk8 + q;
            Us[col][kk8 + q] = (j < 300 && k < 300) ? U[urow * 300 + k] : 0.0f;
        }
#pragma unroll
        for (int q = 0; q < 4; q++) {
            int k = k0 + kk4 + q;
            Hs[bi][kk4 + q] = (k < 300) ? hin[(b0 + bi) * 300 + k] : 0.0f;
        }
        __syncthreads();
#pragma unroll
        for (int kk = 0; kk < 32; kk++) {
            float u = Us[col][kk];
#pragma unroll
            for (int i = 0; i < 8; i++)
                acc[i] += u * Hs[bg * 8 + i][kk];
        }
    }
#pragma unroll
    for (int i = 0; i < 8; i++) {
        int bA = b0 + bg * 8 + i;
        float p = acc[i];
        if (j < 300) p += G[(size_t)(tt * 128 + bA) * 1200 + urow];
        P[bg * 8 + i][col] = p;
    }
    __syncthreads();
#pragma unroll
    for (int ii = 0; ii < 2; ii++) {
        int p = tid + 256 * ii;
        int bl = p >> 4, j2 = p & 15;
        int jj = j0 + j2;
        if (jj < 300) {
            float gi = P[bl][j2], gf = P[bl][16 + j2], gg = P[bl][32 + j2], go = P[bl][48 + j2];
            int ci = (b0 + bl) * 300 + jj;
            float cn = sigf(gf) * c[ci] + sigf(gi) * tanhf(gg);
            float hn = sigf(go) * tanhf(cn);
            c[ci] = cn;
            hout[ci] = hn;
        }
    }
}

// ---------------- encoder context build (seq-major rows, masked) ----------------
__global__ __launch_bounds__(256) void ctx_k(const float* __restrict__ hF,
                                             const float* __restrict__ hR,
                                             const float* __restrict__ x1m,
                                             const float* __restrict__ x2m,
                                             float* __restrict__ ctx) {
    int idx = blockIdx.x * 256 + threadIdx.x;
    if (idx >= MR * 600) return;
    int r = idx / 600, d = idx % 600;
    int seq = r / 3072, rem = r % 3072;
    int t = rem / 64, b = rem & 63;
    int bc = seq * 64 + b;
    float v = (d < 300) ? hF[bc * 300 + d] : hR[(seq * 64 + 63 - b) * 300 + d - 300];
    float mk = seq ? x2m[t * 64 + b] : x1m[t * 64 + b];
    ctx[idx] = v * mk;
}

// ---------------- scores[b][i][j] = max_d c1[b,i,d]*c2[b,j,d] ----------------
__global__ __launch_bounds__(256) void scores_k(const float* __restrict__ ctx,
                                                float* __restrict__ sc) {
    int i = blockIdx.x, b = blockIdx.y;
    __shared__ float c1s[600];
    __shared__ float c2s[48][121];
    int tid = threadIdx.x;
    for (int d = tid; d < 600; d += 256) c1s[d] = ctx[(i * 64 + b) * 600 + d];
    float m = -3.4e38f;
    for (int d0 = 0; d0 < 600; d0 += 120) {
        __syncthreads();
        for (int q = tid; q < 48 * 120; q += 256) {
            int j = q / 120, dd = q % 120;
            c2s[j][dd] = ctx[(3072 + j * 64 + b) * 600 + d0 + dd];
        }
        __syncthreads();
        if (tid < 48) {
            for (int dd = 0; dd < 120; dd++)
                m = fmaxf(m, c1s[d0 + dd] * c2s[tid][dd]);
        }
    }
    if (tid < 48) sc[(b * 48 + i) * 48 + tid] = m;
}

// ---------------- alpha softmax (axis j) + a_tilde = max_j alpha*c2 ----------------
__global__ __launch_bounds__(256) void att_a(const float* __restrict__ sc,
                                             const float* __restrict__ ctx,
                                             const float* __restrict__ x2m,
                                             float* __restrict__ at) {
    int i = blockIdx.x, b = blockIdx.y;
    __shared__ float alpha[48];
    __shared__ float red;
    __shared__ float c2s[48][121];
    int tid = threadIdx.x;
    if (tid < 48) alpha[tid] = sc[(b * 48 + i) * 48 + tid];
    __syncthreads();
    if (tid == 0) {
        float mx = alpha[0];
        for (int j = 1; j < 48; j++) mx = fmaxf(mx, alpha[j]);
        red = mx;
    }
    __syncthreads();
    if (tid < 48) alpha[tid] = expf(alpha[tid] - red) * x2m[tid * 64 + b];
    __syncthreads();
    if (tid == 0) {
        float s = 0;
        for (int j = 0; j < 48; j++) s += alpha[j];
        red = s;
    }
    __syncthreads();
    if (tid < 48) alpha[tid] /= red;
    for (int d0 = 0; d0 < 600; d0 += 120) {
        __syncthreads();
        for (int q = tid; q < 48 * 120; q += 256) {
            int j = q / 120, dd = q % 120;
            c2s[j][dd] = ctx[(3072 + j * 64 + b) * 600 + d0 + dd];
        }
        __syncthreads();
        if (tid < 120) {
            float m = -3.4e38f;
#pragma unroll
            for (int j = 0; j < 48; j++) m = fmaxf(m, alpha[j] * c2s[j][tid]);
            at[(i * 64 + b) * 600 + d0 + tid] = m;
        }
    }
}

// ---------------- beta softmax (axis i) + b_tilde = sum_i beta*c1 ----------------
__global__ __launch_bounds__(256) void att_b(const float* __restrict__ sc,
                                             const float* __restrict__ ctx,
                                             const float* __restrict__ x1m,
                                             float* __restrict__ at) {
    int jj = blockIdx.x, b = blockIdx.y;
    __shared__ float beta[48];
    __shared__ float red;
    __shared__ float c1s[48][121];
    int tid = threadIdx.x;
    if (tid < 48) beta[tid] = sc[(b * 48 + tid) * 48 + jj];
    __syncthreads();
    if (tid == 0) {
        float mx = beta[0];
        for (int i2 = 1; i2 < 48; i2++) mx = fmaxf(mx, beta[i2]);
        red = mx;
    }
    __syncthreads();
    if (tid < 48) beta[tid] = expf(beta[tid] - red) * x1m[tid * 64 + b];
    __syncthreads();
    if (tid == 0) {
        float s = 0;
        for (int i2 = 0; i2 < 48; i2++) s += beta[i2];
        red = s;
    }
    __syncthreads();
    if (tid < 48) beta[tid] /= red;
    for (int d0 = 0; d0 < 600; d0 += 120) {
        __syncthreads();
        for (int q = tid; q < 48 * 120; q += 256) {
            int i2 = q / 120, dd = q % 120;
            c1s[i2][dd] = ctx[(i2 * 64 + b) * 600 + d0 + dd];
        }
        __syncthreads();
        if (tid < 120) {
            float s = 0;
#pragma unroll
            for (int i2 = 0; i2 < 48; i2++) s += beta[i2] * c1s[i2][tid];
            at[(3072 + jj * 64 + b) * 600 + d0 + tid] = s;
        }
    }
}

// ---------------- decoder context build (quirk: batch-reversed reverse hidden) ----------------
__global__ __launch_bounds__(256) void dctx_k(const float* __restrict__ hF,
                                              const float* __restrict__ hR,
                                              float* __restrict__ dctx) {
    int idx = blockIdx.x * 256 + threadIdx.x;
    if (idx >= 128 * 600) return;
    int bc = idx / 600, d = idx % 600;
    int seq = bc >> 6, b = bc & 63;
    dctx[idx] = (d < 300) ? hF[bc * 300 + d] : hR[(seq * 64 + 63 - b) * 300 + d - 300];
}

// ---------------- masked mean/max pooling -> pooled[64][2400] ----------------
__global__ __launch_bounds__(256) void pool_k(const float* __restrict__ dctx,
                                              const float* __restrict__ x1m,
                                              const float* __restrict__ x2m,
                                              float* __restrict__ pooled) {
    int idx = blockIdx.x * 256 + threadIdx.x;
    if (idx >= 64 * 2400) return;
    int b = idx / 2400, col = idx % 2400;
    int sec = col / 600, d = col % 600;
    const float* msk = (sec < 2) ? x1m : x2m;
    float v = dctx[((sec < 2 ? 0 : 64) + b) * 600 + d];
    float out;
    if ((sec & 1) == 0) {
        float s = 0, sm = 0;
        for (int t = 0; t < 48; t++) { float mv = msk[t * 64 + b]; s += v * mv; sm += mv; }
        out = s / sm;
    } else {
        float m = -3.4e38f;
        for (int t = 0; t < 48; t++) m = fmaxf(m, v * msk[t * 64 + b]);
        out = m;
    }
    pooled[idx] = out;
}

// ---------------- fc2 + tanh ----------------
__global__ __launch_bounds__(256) void fc2_k(const float* __restrict__ pooled,
                                             const float* __restrict__ f2w,
                                             const float* __restrict__ f2b,
                                             float* __restrict__ logit) {
    __shared__ float ps[64][33];
    int tid = threadIdx.x;
    int b = tid & 63, nl = tid >> 6;
    int n = blockIdx.x * 4 + nl;
    int lrow = tid >> 2, lk = (tid & 3) << 3;
    float acc = 0;
    for (int k0 = 0; k0 < 2400; k0 += 32) {
        __syncthreads();
#pragma unroll
        for (int q = 0; q < 8; q++)
            ps[lrow][lk + q] = pooled[lrow * 2400 + k0 + lk + q];
        __syncthreads();
#pragma unroll
        for (int kk = 0; kk < 32; kk++)
            acc += ps[b][kk] * f2w[n * 2400 + k0 + kk];
    }
    logit[b * 300 + n] = tanhf(acc + f2b[n]);
}

// ---------------- output layer ----------------
__global__ __launch_bounds__(256) void out_k(const float* __restrict__ logit,
                                             const float* __restrict__ fow,
                                             const float* __restrict__ fob,
                                             float* __restrict__ out) {
    int tid = threadIdx.x;
    if (tid < 192) {
        int b = tid / 3, o = tid % 3;
        float acc = fob[o];
        for (int k = 0; k < 300; k++) acc += logit[b * 300 + k] * fow[o * 300 + k];
        out[tid] = acc;
    }
}

extern "C" void kernel_launch(void* const* d_in, const int* in_sizes, int n_in,
                              void* d_out, int out_size, void* d_ws, size_t ws_size,
                              hipStream_t stream) {
    (void)in_sizes; (void)n_in; (void)out_size; (void)ws_size;
    const int*   x1  = (const int*)d_in[0];
    const float* x1m = (const float*)d_in[1];
    const int*   x2  = (const int*)d_in[2];
    const float* x2m = (const float*)d_in[3];
    const float* emb = (const float*)d_in[5];
    const float* eW  = (const float*)d_in[6];
    const float* eU  = (const float*)d_in[7];
    const float* ebi = (const float*)d_in[8];
    const float* ebh = (const float*)d_in[9];
    const float* rW  = (const float*)d_in[10];
    const float* rU  = (const float*)d_in[11];
    const float* rbi = (const float*)d_in[12];
    const float* rbh = (const float*)d_in[13];
    const float* dW  = (const float*)d_in[14];
    const float* dU  = (const float*)d_in[15];
    const float* dbi = (const float*)d_in[16];
    const float* dbh = (const float*)d_in[17];
    const float* sW  = (const float*)d_in[18];
    const float* sU  = (const float*)d_in[19];
    const float* sbi = (const float*)d_in[20];
    const float* sbh = (const float*)d_in[21];
    const float* f1w = (const float*)d_in[22];
    const float* f1b = (const float*)d_in[23];
    const float* f2w = (const float*)d_in[24];
    const float* f2b = (const float*)d_in[25];
    const float* fow = (const float*)d_in[26];
    const float* fob = (const float*)d_in[27];

    char* wsb = (char*)d_ws;
    u16*   ABF  = (u16*)(wsb + OFF_ABF);
    u16*   WBF  = (u16*)(wsb + OFF_WBF);      // 4 segments of 1280*320
    u16*   WCBF = (u16*)(wsb + OFF_WCBF);
    float* GF   = (float*)(wsb + OFF_GF);
    float* GR   = (float*)(wsb + OFF_GR);
    float* ST   = (float*)(wsb + OFF_ST);
    float* CTX  = (float*)(wsb + OFF_CTX);
    float* AT   = (float*)(wsb + OFF_AT);
    float* SC   = (float*)(wsb + OFF_SC);
    float* DCTX = (float*)(wsb + OFF_DCTX);
    float* POOL = (float*)(wsb + OFF_POOL);
    float* LOGIT= (float*)(wsb + OFF_LOGIT);
    u16*   ACAT = (u16*)GF;                   // alias: GF dead between enc recurrence and dec proj

    float* HF0 = ST;
    float* HR0 = ST + 38400;
    float* CF  = ST + 76800;
    float* CR  = ST + 115200;
    float* HF1 = ST + 153600;
    float* HR1 = ST + 192000;

    const int WSEG = NP1 * KP1;   // 409600 u16 per weight segment

    // conversions
    gather_bf<<<dim3((MR * KP1 + 255) / 256), 256, 0, stream>>>(x1, x2, emb, ABF);
    wconv_k<<<dim3((4 * NP1 * KP1 + 255) / 256), 256, 0, stream>>>(eW, rW, dW, sW, WBF);
    wcat_bf<<<dim3((NP2 * KP2 + 255) / 256), 256, 0, stream>>>(f1w, WCBF);

    // zero h0/c0
    hipMemsetAsync(ST, 0, 4 * 38400 * sizeof(float), stream);

    // encoder input projections (MFMA)
    gemm_bt<<<dim3(48, NP1 / 128), 256, 0, stream>>>(ABF, WBF,            ebi, ebh, GF, 1200, KP1);
    gemm_bt<<<dim3(48, NP1 / 128), 256, 0, stream>>>(ABF, WBF + WSEG,     rbi, rbh, GR, 1200, KP1);

    // encoder recurrence
    for (int t = 0; t < 48; t++) {
        const float* hinF = (t & 1) ? HF1 : HF0;
        float*       houtF = (t & 1) ? HF0 : HF1;
        const float* hinR = (t & 1) ? HR1 : HR0;
        float*       houtR = (t & 1) ? HR0 : HR1;
        lstm_step<<<dim3(19, 4, 2), 256, 0, stream>>>(GF, GR, eU, rU, hinF, houtF, hinR, houtR, CF, CR, t);
    }

    // contexts + attention
    ctx_k<<<dim3((MR * 600 + 255) / 256), 256, 0, stream>>>(HF0, HR0, x1m, x2m, CTX);
    scores_k<<<dim3(48, 64), 256, 0, stream>>>(CTX, SC);
    att_a<<<dim3(48, 64), 256, 0, stream>>>(SC, CTX, x2m, AT);
    att_b<<<dim3(48, 64), 256, 0, stream>>>(SC, CTX, x1m, AT);

    // fc1: build bf16 concat A (aliases GF), MFMA gemm -> bf16 h1 into ABF (t-major)
    acat_k<<<dim3((MR * KP2 + 255) / 256), 256, 0, stream>>>(CTX, AT, ACAT);
    gemm_fc1_bt<<<dim3(48, NP2 / 128), 256, 0, stream>>>(ACAT, WCBF, f1b, ABF);

    // decoder phase
    hipMemsetAsync(ST, 0, 4 * 38400 * sizeof(float), stream);
    gemm_bt<<<dim3(48, NP1 / 128), 256, 0, stream>>>(ABF, WBF + 2 * WSEG, dbi, dbh, GF, 1200, KP1);
    gemm_bt<<<dim3(48, NP1 / 128), 256, 0, stream>>>(ABF, WBF + 3 * WSEG, sbi, sbh, GR, 1200, KP1);
    for (int t = 0; t < 48; t++) {
        const float* hinF = (t & 1) ? HF1 : HF0;
        float*       houtF = (t & 1) ? HF0 : HF1;
        const float* hinR = (t & 1) ? HR1 : HR0;
        float*       houtR = (t & 1) ? HR0 : HR1;
        lstm_step<<<dim3(19, 4, 2), 256, 0, stream>>>(GF, GR, dU, sU, hinF, houtF, hinR, houtR, CF, CR, t);
    }

    // pooling + classifier
    dctx_k<<<dim3((128 * 600 + 255) / 256), 256, 0, stream>>>(HF0, HR0, DCTX);
    pool_k<<<dim3((64 * 2400 + 255) / 256), 256, 0, stream>>>(DCTX, x1m, x2m, POOL);
    fc2_k<<<dim3(75), 256, 0, stream>>>(POOL, f2w, f2b, LOGIT);
    out_k<<<dim3(1), 256, 0, stream>>>(LOGIT, fow, fob, (float*)d_out);
}

// Round 3
// 3133.779 us; speedup vs baseline: 1.7082x; 1.4566x over previous
//
#include <hip/hip_runtime.h>
#include <math.h>

typedef unsigned short u16;
typedef __attribute__((ext_vector_type(8))) __bf16 bf16x8;
typedef __attribute__((ext_vector_type(4))) float f32x4;

// ---------------- problem constants ----------------
#define MR   6144      // 48*128 rows (t-major: row = t*128 + bc)
#define KP1  320       // padded K for E=H=300
#define NPG  1280      // padded gate rows (1200 real, interleaved 4j+g)
#define NG   1200
#define KP2  1824      // padded K for 3*600=1800 (fc1 folded)
#define NP2  384       // padded N for H=300 (fc1)
#define WSEG 409600    // u16 elements per weight segment [1280][320]

// ---------------- workspace layout (byte offsets) ----------------
#define OFF_ABF    0UL          // bf16 [6144][320]          3,932,160
#define OFF_WBF    3932160UL    // bf16 8 x [1280][320]      6,553,600 (eW,rW,dW,sW,eU,rU,dU,sU interleaved)
#define OFF_WCBF   10485760UL   // bf16 [384][1824]          1,400,832
#define OFF_BIAS   11886592UL   // f32  4 x 1200 (interleaved, bi+bh)  19,200 -> pad 20,480
#define OFF_GF     11907072UL   // f32  [6144][1200]        29,491,200  (aliased by ACAT bf16 [6144][1824])
#define OFF_GR     41398272UL   // f32  [6144][1200]        29,491,200  (aliased by CTX+AT after enc recurrence)
#define OFF_HB     70889472UL   // bf16 2 bufs x 2 dirs x [128][320]   327,680
#define OFF_CC     71217152UL   // f32  2 dirs x 128*300               307,200
#define OFF_SC     71524352UL   // f32  64*48*48                       589,824
#define OFF_DCTX   72114176UL   // f32  128*600                        307,200
#define OFF_POOL   72421376UL   // f32  64*2400                        614,400
#define OFF_LOGIT  73035776UL   // f32  64*300                          76,800

__device__ __forceinline__ float sigf(float x) { return 1.0f / (1.0f + expf(-x)); }

__device__ __forceinline__ u16 f2bf(float x) {
    union { float f; unsigned int u; } v; v.f = x;
    unsigned int r = v.u + 0x7fffu + ((v.u >> 16) & 1u);   // RNE
    return (u16)(r >> 16);
}
__device__ __forceinline__ float bf2f(u16 x) {
    union { unsigned int u; float f; } v; v.u = ((unsigned int)x) << 16; return v.f;
}

__device__ __forceinline__ void gld_lds16(const u16* g, u16* l) {
    __builtin_amdgcn_global_load_lds(
        (const __attribute__((address_space(1))) unsigned int*)g,
        (__attribute__((address_space(3))) unsigned int*)l, 16, 0, 0);
}

// ---------------- embedding gather -> bf16, K zero-padded ----------------
__global__ __launch_bounds__(256) void gather_bf(const int* __restrict__ x1,
                                                 const int* __restrict__ x2,
                                                 const float* __restrict__ emb,
                                                 u16* __restrict__ abf) {
    int idx = blockIdx.x * 256 + threadIdx.x;
    if (idx >= MR * KP1) return;
    int r = idx / KP1, k = idx % KP1;
    float v = 0.0f;
    if (k < 300) {
        int t = r >> 7, bc = r & 127;
        int tok = (bc < 64) ? x1[t * 64 + bc] : x2[t * 64 + bc - 64];
        v = emb[tok * 300 + k];
    }
    abf[idx] = f2bf(v);
}

// ---------------- 8 weight matrices [1200][300] -> gate-interleaved bf16 [1280][320] ----------------
__global__ __launch_bounds__(256) void wconv8_k(const float* __restrict__ w0, const float* __restrict__ w1,
                                                const float* __restrict__ w2, const float* __restrict__ w3,
                                                const float* __restrict__ w4, const float* __restrict__ w5,
                                                const float* __restrict__ w6, const float* __restrict__ w7,
                                                u16* __restrict__ out) {
    int idx = blockIdx.x * 256 + threadIdx.x;
    if (idx >= 8 * NPG * KP1) return;
    int s = idx / (NPG * KP1), rem = idx % (NPG * KP1);
    int r = rem / KP1, k = rem % KP1;
    const float* w = (s == 0) ? w0 : (s == 1) ? w1 : (s == 2) ? w2 : (s == 3) ? w3
                   : (s == 4) ? w4 : (s == 5) ? w5 : (s == 6) ? w6 : w7;
    float v = 0.0f;
    if (r < NG && k < 300) {
        int j = r >> 2, g = r & 3;           // interleaved row 4j+g <- source row g*300+j
        v = w[(g * 300 + j) * 300 + k];
    }
    out[idx] = f2bf(v);
}

// ---------------- 4 bias pairs -> interleaved f32 [4][1200] ----------------
__global__ __launch_bounds__(256) void bconv_k(const float* __restrict__ b0i, const float* __restrict__ b0h,
                                               const float* __restrict__ b1i, const float* __restrict__ b1h,
                                               const float* __restrict__ b2i, const float* __restrict__ b2h,
                                               const float* __restrict__ b3i, const float* __restrict__ b3h,
                                               float* __restrict__ out) {
    int idx = blockIdx.x * 256 + threadIdx.x;
    if (idx >= 4 * NG) return;
    int s = idx / NG, n = idx % NG;
    int j = n >> 2, g = n & 3;
    int src = g * 300 + j;
    const float* bi = (s == 0) ? b0i : (s == 1) ? b1i : (s == 2) ? b2i : b3i;
    const float* bh = (s == 0) ? b0h : (s == 1) ? b1h : (s == 2) ? b2h : b3h;
    out[idx] = bi[src] + bh[src];
}

// ---------------- folded fc1 weight -> bf16 [384][1824] ----------------
__global__ __launch_bounds__(256) void wcat_bf(const float* __restrict__ f1w,
                                               u16* __restrict__ wc) {
    int idx = blockIdx.x * 256 + threadIdx.x;
    if (idx >= NP2 * KP2) return;
    int n = idx / KP2, k = idx % KP2;
    float v = 0.0f;
    if (n < 300 && k < 1800) {
        int nk = n * 2400 + k;
        if (k < 600)       v = f1w[nk] + f1w[nk + 1800];   // c coeff: W1+W4
        else if (k < 1200) v = f1w[nk] - f1w[nk + 1200];   // a coeff: W2-W4
        else               v = f1w[nk];                    // c*a coeff: W3
    }
    wc[idx] = f2bf(v);
}

// ---------------- bf16 MFMA GEMM: C[M][1200] f32 = A@B^T + bias (N guarded to 1200) ----------------
__global__ __launch_bounds__(256) void gemm_bt(const u16* __restrict__ A,
                                               const u16* __restrict__ B,
                                               const float* __restrict__ bias,
                                               float* __restrict__ C,
                                               int N, int Kpad) {
    __shared__ __align__(16) u16 smA[128 * 32];
    __shared__ __align__(16) u16 smB[128 * 32];
    int m0 = blockIdx.x * 128, n0 = blockIdx.y * 128;
    int tid = threadIdx.x, ln = tid & 63;
    int wm = (tid >> 6) & 1, wn = tid >> 7;
    int lrow = ln & 15, lq = ln >> 4;
    f32x4 acc[4][4] = {};
    for (int k0 = 0; k0 < Kpad; k0 += 32) {
#pragma unroll
        for (int p = 0; p < 2; p++) {
            int e = (p * 256 + tid) * 8;
            int r = e >> 5, kk = e & 31;
            gld_lds16(A + (size_t)(m0 + r) * Kpad + k0 + kk, smA + e);
            gld_lds16(B + (size_t)(n0 + r) * Kpad + k0 + kk, smB + e);
        }
        __syncthreads();
        bf16x8 av[4], bv[4];
#pragma unroll
        for (int i = 0; i < 4; i++) {
            av[i] = *(const bf16x8*)&smA[(wm * 64 + i * 16 + lrow) * 32 + lq * 8];
            bv[i] = *(const bf16x8*)&smB[(wn * 64 + i * 16 + lrow) * 32 + lq * 8];
        }
#pragma unroll
        for (int i = 0; i < 4; i++)
#pragma unroll
            for (int j = 0; j < 4; j++)
                acc[i][j] = __builtin_amdgcn_mfma_f32_16x16x32_bf16(av[i], bv[j], acc[i][j], 0, 0, 0);
        __syncthreads();
    }
#pragma unroll
    for (int i = 0; i < 4; i++)
#pragma unroll
        for (int j = 0; j < 4; j++) {
            int n = n0 + wn * 64 + j * 16 + lrow;
            if (n < N) {
                float bb = bias[n];
#pragma unroll
                for (int r = 0; r < 4; r++) {
                    int m = m0 + wm * 64 + i * 16 + lq * 4 + r;
                    C[(size_t)m * N + n] = acc[i][j][r] + bb;
                }
            }
        }
}

// ---------------- fc1 MFMA GEMM: relu(A@Wc^T + b) -> bf16 t-major [6144][320] ----------------
__global__ __launch_bounds__(256) void gemm_fc1_bt(const u16* __restrict__ A,
                                                   const u16* __restrict__ B,
                                                   const float* __restrict__ bias,
                                                   u16* __restrict__ OUT) {
    __shared__ __align__(16) u16 smA[128 * 32];
    __shared__ __align__(16) u16 smB[128 * 32];
    const int Kpad = KP2;
    int m0 = blockIdx.x * 128, n0 = blockIdx.y * 128;
    int tid = threadIdx.x, ln = tid & 63;
    int wm = (tid >> 6) & 1, wn = tid >> 7;
    int lrow = ln & 15, lq = ln >> 4;
    f32x4 acc[4][4] = {};
    for (int k0 = 0; k0 < Kpad; k0 += 32) {
#pragma unroll
        for (int p = 0; p < 2; p++) {
            int e = (p * 256 + tid) * 8;
            int r = e >> 5, kk = e & 31;
            gld_lds16(A + (size_t)(m0 + r) * Kpad + k0 + kk, smA + e);
            gld_lds16(B + (size_t)(n0 + r) * Kpad + k0 + kk, smB + e);
        }
        __syncthreads();
        bf16x8 av[4], bv[4];
#pragma unroll
        for (int i = 0; i < 4; i++) {
            av[i] = *(const bf16x8*)&smA[(wm * 64 + i * 16 + lrow) * 32 + lq * 8];
            bv[i] = *(const bf16x8*)&smB[(wn * 64 + i * 16 + lrow) * 32 + lq * 8];
        }
#pragma unroll
        for (int i = 0; i < 4; i++)
#pragma unroll
            for (int j = 0; j < 4; j++)
                acc[i][j] = __builtin_amdgcn_mfma_f32_16x16x32_bf16(av[i], bv[j], acc[i][j], 0, 0, 0);
        __syncthreads();
    }
#pragma unroll
    for (int i = 0; i < 4; i++)
#pragma unroll
        for (int j = 0; j < 4; j++) {
            int n = n0 + wn * 64 + j * 16 + lrow;
            if (n < 300) {
                float bb = bias[n];
#pragma unroll
                for (int r = 0; r < 4; r++) {
                    int m = m0 + wm * 64 + i * 16 + lq * 4 + r;     // seq-major row
                    int seq = m / 3072, rem = m % 3072;
                    int t = rem / 64, bidx = rem & 63;
                    int orow = t * 128 + seq * 64 + bidx;           // t-major for decoder
                    float v = fmaxf(acc[i][j][r] + bb, 0.0f);
                    OUT[(size_t)orow * KP1 + n] = f2bf(v);
                }
            }
        }
}

// ---------------- build fc1 A = [ctx | at | ctx*at] bf16, K zero-padded ----------------
__global__ __launch_bounds__(256) void acat_k(const float* __restrict__ ctx,
                                              const float* __restrict__ at,
                                              u16* __restrict__ acat) {
    int idx = blockIdx.x * 256 + threadIdx.x;
    if (idx >= MR * KP2) return;
    int r = idx / KP2, k = idx % KP2;
    float v = 0.0f;
    if (k < 600)        v = ctx[r * 600 + k];
    else if (k < 1200)  v = at[r * 600 + k - 600];
    else if (k < 1800) { int k2 = k - 1200; v = ctx[r * 600 + k2] * at[r * 600 + k2]; }
    acat[idx] = f2bf(v);
}

// ---------------- MFMA LSTM step: gates = h@U'^T + G', fused nonlinearity ----------------
// grid (10 n-tiles, 2 dirs), block 256. U' gate-interleaved [1280][320] bf16.
// G gate-interleaved f32 [t][128][1200]. h bf16 [128][320], c f32 [128][300].
__global__ __launch_bounds__(256) void lstm_mfma(const float* __restrict__ Gf,
                                                 const float* __restrict__ Gr,
                                                 const u16* __restrict__ Uf,
                                                 const u16* __restrict__ Ur,
                                                 const u16* __restrict__ hinF,
                                                 const u16* __restrict__ hinR,
                                                 u16* __restrict__ houtF,
                                                 u16* __restrict__ houtR,
                                                 float* __restrict__ cF,
                                                 float* __restrict__ cR,
                                                 int t) {
    int dir = blockIdx.y;
    const float* G = dir ? Gr : Gf;
    const u16* U = dir ? Ur : Uf;
    const u16* hin = dir ? hinR : hinF;
    u16* hout = dir ? houtR : houtF;
    float* c = dir ? cR : cF;
    int tt = dir ? 47 - t : t;

    __shared__ __align__(16) u16 smA[128 * 32];
    __shared__ __align__(16) u16 smB[128 * 32];
    __shared__ float P[128][128];

    int n0 = blockIdx.x * 128;
    int tid = threadIdx.x, ln = tid & 63;
    int wm = (tid >> 6) & 1, wn = tid >> 7;
    int lrow = ln & 15, lq = ln >> 4;
    f32x4 acc[4][4] = {};
    for (int k0 = 0; k0 < KP1; k0 += 32) {
#pragma unroll
        for (int p = 0; p < 2; p++) {
            int e = (p * 256 + tid) * 8;
            int r = e >> 5, kk = e & 31;
            gld_lds16(hin + (size_t)r * KP1 + k0 + kk, smA + e);
            gld_lds16(U + (size_t)(n0 + r) * KP1 + k0 + kk, smB + e);
        }
        __syncthreads();
        bf16x8 av[4], bv[4];
#pragma unroll
        for (int i = 0; i < 4; i++) {
            av[i] = *(const bf16x8*)&smA[(wm * 64 + i * 16 + lrow) * 32 + lq * 8];
            bv[i] = *(const bf16x8*)&smB[(wn * 64 + i * 16 + lrow) * 32 + lq * 8];
        }
#pragma unroll
        for (int i = 0; i < 4; i++)
#pragma unroll
            for (int j = 0; j < 4; j++)
                acc[i][j] = __builtin_amdgcn_mfma_f32_16x16x32_bf16(av[i], bv[j], acc[i][j], 0, 0, 0);
        __syncthreads();
    }
    // stage gate preacts (+G) into LDS
#pragma unroll
    for (int i = 0; i < 4; i++)
#pragma unroll
        for (int j = 0; j < 4; j++) {
            int nl = wn * 64 + j * 16 + lrow;
            int n = n0 + nl;
#pragma unroll
            for (int r = 0; r < 4; r++) {
                int m = wm * 64 + i * 16 + lq * 4 + r;
                float g = (n < NG) ? G[(size_t)(tt * 128 + m) * NG + n] : 0.0f;
                P[m][nl] = acc[i][j][r] + g;
            }
        }
    __syncthreads();
    // gate nonlinearity: thread (jl, bg) handles 16 batch rows of dim jglob
    int jl = tid & 31, bg = tid >> 5;
    int jglob = (n0 >> 2) + jl;
    if (jglob < 300) {
#pragma unroll
        for (int bb = 0; bb < 16; bb++) {
            int b = bg * 16 + bb;
            f32x4 gv = *(const f32x4*)&P[b][4 * jl];    // i,f,g,o
            int ci = b * 300 + jglob;
            float cn = sigf(gv[1]) * c[ci] + sigf(gv[0]) * tanhf(gv[2]);
            float hn = sigf(gv[3]) * tanhf(cn);
            c[ci] = cn;
            hout[(size_t)b * KP1 + jglob] = f2bf(hn);
        }
    }
}

// ---------------- encoder context build (seq-major rows, masked), bf16 h -> f32 ----------------
__global__ __launch_bounds__(256) void ctx_k(const u16* __restrict__ hF,
                                             const u16* __restrict__ hR,
                                             const float* __restrict__ x1m,
                                             const float* __restrict__ x2m,
                                             float* __restrict__ ctx) {
    int idx = blockIdx.x * 256 + threadIdx.x;
    if (idx >= MR * 600) return;
    int r = idx / 600, d = idx % 600;
    int seq = r / 3072, rem = r % 3072;
    int t = rem / 64, b = rem & 63;
    int bc = seq * 64 + b;
    float v = (d < 300) ? bf2f(hF[bc * KP1 + d])
                        : bf2f(hR[(seq * 64 + 63 - b) * KP1 + d - 300]);
    float mk = seq ? x2m[t * 64 + b] : x1m[t * 64 + b];
    ctx[idx] = v * mk;
}

// ---------------- scores[b][i][j] = max_d c1[b,i,d]*c2[b,j,d] (240 compute threads) ----------------
__global__ __launch_bounds__(256) void scores_k2(const float* __restrict__ ctx,
                                                 float* __restrict__ sc) {
    int i = blockIdx.x, b = blockIdx.y;
    __shared__ float c1s[600];
    __shared__ float c2s[48][121];
    __shared__ float pm[48][5];
    int tid = threadIdx.x;
    for (int d = tid; d < 600; d += 256) c1s[d] = ctx[(i * 64 + b) * 600 + d];
    int jt = tid / 5, s5 = tid - jt * 5;
    float m = -3.4e38f;
    for (int d0 = 0; d0 < 600; d0 += 120) {
        __syncthreads();
        for (int q = tid; q < 48 * 120; q += 256) {
            int j = q / 120, dd = q % 120;
            c2s[j][dd] = ctx[(3072 + j * 64 + b) * 600 + d0 + dd];
        }
        __syncthreads();
        if (tid < 240) {
#pragma unroll
            for (int dd = s5 * 24; dd < s5 * 24 + 24; dd++)
                m = fmaxf(m, c1s[d0 + dd] * c2s[jt][dd]);
        }
    }
    if (tid < 240) pm[jt][s5] = m;
    __syncthreads();
    if (tid < 48)
        sc[(b * 48 + i) * 48 + tid] =
            fmaxf(fmaxf(fmaxf(pm[tid][0], pm[tid][1]), fmaxf(pm[tid][2], pm[tid][3])), pm[tid][4]);
}

// ---------------- alpha softmax (axis j) + a_tilde = max_j alpha*c2 ----------------
__global__ __launch_bounds__(256) void att_a(const float* __restrict__ sc,
                                             const float* __restrict__ ctx,
                                             const float* __restrict__ x2m,
                                             float* __restrict__ at) {
    int i = blockIdx.x, b = blockIdx.y;
    __shared__ float alpha[48];
    __shared__ float red;
    __shared__ float c2s[48][121];
    int tid = threadIdx.x;
    if (tid < 48) alpha[tid] = sc[(b * 48 + i) * 48 + tid];
    __syncthreads();
    if (tid == 0) {
        float mx = alpha[0];
        for (int j = 1; j < 48; j++) mx = fmaxf(mx, alpha[j]);
        red = mx;
    }
    __syncthreads();
    if (tid < 48) alpha[tid] = expf(alpha[tid] - red) * x2m[tid * 64 + b];
    __syncthreads();
    if (tid == 0) {
        float s = 0;
        for (int j = 0; j < 48; j++) s += alpha[j];
        red = s;
    }
    __syncthreads();
    if (tid < 48) alpha[tid] /= red;
    for (int d0 = 0; d0 < 600; d0 += 120) {
        __syncthreads();
        for (int q = tid; q < 48 * 120; q += 256) {
            int j = q / 120, dd = q % 120;
            c2s[j][dd] = ctx[(3072 + j * 64 + b) * 600 + d0 + dd];
        }
        __syncthreads();
        if (tid < 120) {
            float m = -3.4e38f;
#pragma unroll
            for (int j = 0; j < 48; j++) m = fmaxf(m, alpha[j] * c2s[j][tid]);
            at[(i * 64 + b) * 600 + d0 + tid] = m;
        }
    }
}

// ---------------- beta softmax (axis i) + b_tilde = sum_i beta*c1 ----------------
__global__ __launch_bounds__(256) void att_b(const float* __restrict__ sc,
                                             const float* __restrict__ ctx,
                                             const float* __restrict__ x1m,
                                             float* __restrict__ at) {
    int jj = blockIdx.x, b = blockIdx.y;
    __shared__ float beta[48];
    __shared__ float red;
    __shared__ float c1s[48][121];
    int tid = threadIdx.x;
    if (tid < 48) beta[tid] = sc[(b * 48 + tid) * 48 + jj];
    __syncthreads();
    if (tid == 0) {
        float mx = beta[0];
        for (int i2 = 1; i2 < 48; i2++) mx = fmaxf(mx, beta[i2]);
        red = mx;
    }
    __syncthreads();
    if (tid < 48) beta[tid] = expf(beta[tid] - red) * x1m[tid * 64 + b];
    __syncthreads();
    if (tid == 0) {
        float s = 0;
        for (int i2 = 0; i2 < 48; i2++) s += beta[i2];
        red = s;
    }
    __syncthreads();
    if (tid < 48) beta[tid] /= red;
    for (int d0 = 0; d0 < 600; d0 += 120) {
        __syncthreads();
        for (int q = tid; q < 48 * 120; q += 256) {
            int i2 = q / 120, dd = q % 120;
            c1s[i2][dd] = ctx[(i2 * 64 + b) * 600 + d0 + dd];
        }
        __syncthreads();
        if (tid < 120) {
            float s = 0;
#pragma unroll
            for (int i2 = 0; i2 < 48; i2++) s += beta[i2] * c1s[i2][tid];
            at[(3072 + jj * 64 + b) * 600 + d0 + tid] = s;
        }
    }
}

// ---------------- decoder context build (quirk: batch-reversed reverse hidden) ----------------
__global__ __launch_bounds__(256) void dctx_k(const u16* __restrict__ hF,
                                              const u16* __restrict__ hR,
                                              float* __restrict__ dctx) {
    int idx = blockIdx.x * 256 + threadIdx.x;
    if (idx >= 128 * 600) return;
    int bc = idx / 600, d = idx % 600;
    int seq = bc >> 6, b = bc & 63;
    dctx[idx] = (d < 300) ? bf2f(hF[bc * KP1 + d])
                          : bf2f(hR[(seq * 64 + 63 - b) * KP1 + d - 300]);
}

// ---------------- masked mean/max pooling -> pooled[64][2400] ----------------
__global__ __launch_bounds__(256) void pool_k(const float* __restrict__ dctx,
                                              const float* __restrict__ x1m,
                                              const float* __restrict__ x2m,
                                              float* __restrict__ pooled) {
    int idx = blockIdx.x * 256 + threadIdx.x;
    if (idx >= 64 * 2400) return;
    int b = idx / 2400, col = idx % 2400;
    int sec = col / 600, d = col % 600;
    const float* msk = (sec < 2) ? x1m : x2m;
    float v = dctx[((sec < 2 ? 0 : 64) + b) * 600 + d];
    float out;
    if ((sec & 1) == 0) {
        float s = 0, sm = 0;
        for (int t = 0; t < 48; t++) { float mv = msk[t * 64 + b]; s += v * mv; sm += mv; }
        out = s / sm;
    } else {
        float m = -3.4e38f;
        for (int t = 0; t < 48; t++) m = fmaxf(m, v * msk[t * 64 + b]);
        out = m;
    }
    pooled[idx] = out;
}

// ---------------- fc2 + tanh ----------------
__global__ __launch_bounds__(256) void fc2_k(const float* __restrict__ pooled,
                                             const float* __restrict__ f2w,
                                             const float* __restrict__ f2b,
                                             float* __restrict__ logit) {
    __shared__ float ps[64][33];
    int tid = threadIdx.x;
    int b = tid & 63, nl = tid >> 6;
    int n = blockIdx.x * 4 + nl;
    int lrow = tid >> 2, lk = (tid & 3) << 3;
    float acc = 0;
    for (int k0 = 0; k0 < 2400; k0 += 32) {
        __syncthreads();
#pragma unroll
        for (int q = 0; q < 8; q++)
            ps[lrow][lk + q] = pooled[lrow * 2400 + k0 + lk + q];
        __syncthreads();
#pragma unroll
        for (int kk = 0; kk < 32; kk++)
            acc += ps[b][kk] * f2w[n * 2400 + k0 + kk];
    }
    logit[b * 300 + n] = tanhf(acc + f2b[n]);
}

// ---------------- output layer ----------------
__global__ __launch_bounds__(256) void out_k(const float* __restrict__ logit,
                                             const float* __restrict__ fow,
                                             const float* __restrict__ fob,
                                             float* __restrict__ out) {
    int tid = threadIdx.x;
    if (tid < 192) {
        int b = tid / 3, o = tid % 3;
        float acc = fob[o];
        for (int k = 0; k < 300; k++) acc += logit[b * 300 + k] * fow[o * 300 + k];
        out[tid] = acc;
    }
}

extern "C" void kernel_launch(void* const* d_in, const int* in_sizes, int n_in,
                              void* d_out, int out_size, void* d_ws, size_t ws_size,
                              hipStream_t stream) {
    (void)in_sizes; (void)n_in; (void)out_size; (void)ws_size;
    const int*   x1  = (const int*)d_in[0];
    const float* x1m = (const float*)d_in[1];
    const int*   x2  = (const int*)d_in[2];
    const float* x2m = (const float*)d_in[3];
    const float* emb = (const float*)d_in[5];
    const float* eW  = (const float*)d_in[6];
    const float* eU  = (const float*)d_in[7];
    const float* ebi = (const float*)d_in[8];
    const float* ebh = (const float*)d_in[9];
    const float* rW  = (const float*)d_in[10];
    const float* rU  = (const float*)d_in[11];
    const float* rbi = (const float*)d_in[12];
    const float* rbh = (const float*)d_in[13];
    const float* dW  = (const float*)d_in[14];
    const float* dU  = (const float*)d_in[15];
    const float* dbi = (const float*)d_in[16];
    const float* dbh = (const float*)d_in[17];
    const float* sW  = (const float*)d_in[18];
    const float* sU  = (const float*)d_in[19];
    const float* sbi = (const float*)d_in[20];
    const float* sbh = (const float*)d_in[21];
    const float* f1w = (const float*)d_in[22];
    const float* f1b = (const float*)d_in[23];
    const float* f2w = (const float*)d_in[24];
    const float* f2b = (const float*)d_in[25];
    const float* fow = (const float*)d_in[26];
    const float* fob = (const float*)d_in[27];

    char* wsb = (char*)d_ws;
    u16*   ABF  = (u16*)(wsb + OFF_ABF);
    u16*   WBF  = (u16*)(wsb + OFF_WBF);
    u16*   WCBF = (u16*)(wsb + OFF_WCBF);
    float* BIAS = (float*)(wsb + OFF_BIAS);
    float* GF   = (float*)(wsb + OFF_GF);
    float* GR   = (float*)(wsb + OFF_GR);
    u16*   HB   = (u16*)(wsb + OFF_HB);
    float* CC   = (float*)(wsb + OFF_CC);
    float* SC   = (float*)(wsb + OFF_SC);
    float* DCTX = (float*)(wsb + OFF_DCTX);
    float* POOL = (float*)(wsb + OFF_POOL);
    float* LOGIT= (float*)(wsb + OFF_LOGIT);
    u16*   ACAT = (u16*)GF;                   // alias: GF dead between enc recurrence and dec proj
    float* CTX  = GR;                         // alias: GR dead after enc recurrence
    float* AT   = GR + (size_t)MR * 600 / 2 * 2;   // = GR + 3,686,400 floats? no:
    AT = GR + 3686400;                        // 6144*600 floats after CTX

    // h double buffers: HB + buf*81920 + dir*40960 (u16 elements)
    u16* HF[2] = { HB,          HB + 81920 };
    u16* HR[2] = { HB + 40960,  HB + 122880 };
    float* CFp = CC;
    float* CRp = CC + 38400;

    // ---- conversions ----
    gather_bf<<<dim3((MR * KP1 + 255) / 256), 256, 0, stream>>>(x1, x2, emb, ABF);
    wconv8_k<<<dim3((8 * NPG * KP1 + 255) / 256), 256, 0, stream>>>(eW, rW, dW, sW, eU, rU, dU, sU, WBF);
    bconv_k<<<dim3((4 * NG + 255) / 256), 256, 0, stream>>>(ebi, ebh, rbi, rbh, dbi, dbh, sbi, sbh, BIAS);
    wcat_bf<<<dim3((NP2 * KP2 + 255) / 256), 256, 0, stream>>>(f1w, WCBF);

    // ---- encoder ----
    hipMemsetAsync(wsb + OFF_HB, 0, 327680 + 307200, stream);    // h bufs + c
    gemm_bt<<<dim3(48, 10), 256, 0, stream>>>(ABF, WBF,            BIAS,        GF, NG, KP1);
    gemm_bt<<<dim3(48, 10), 256, 0, stream>>>(ABF, WBF + WSEG,     BIAS + NG,   GR, NG, KP1);
    for (int t = 0; t < 48; t++) {
        int ib = t & 1, ob = ib ^ 1;
        lstm_mfma<<<dim3(10, 2), 256, 0, stream>>>(GF, GR, WBF + 4 * WSEG, WBF + 5 * WSEG,
                                                   HF[ib], HR[ib], HF[ob], HR[ob], CFp, CRp, t);
    }

    // ---- contexts + attention (final h in buf0 after 48 steps) ----
    ctx_k<<<dim3((MR * 600 + 255) / 256), 256, 0, stream>>>(HF[0], HR[0], x1m, x2m, CTX);
    scores_k2<<<dim3(48, 64), 256, 0, stream>>>(CTX, SC);
    att_a<<<dim3(48, 64), 256, 0, stream>>>(SC, CTX, x2m, AT);
    att_b<<<dim3(48, 64), 256, 0, stream>>>(SC, CTX, x1m, AT);

    // ---- fc1 ----
    acat_k<<<dim3((MR * KP2 + 255) / 256), 256, 0, stream>>>(CTX, AT, ACAT);
    gemm_fc1_bt<<<dim3(48, 3), 256, 0, stream>>>(ACAT, WCBF, f1b, ABF);

    // ---- decoder ----
    hipMemsetAsync(wsb + OFF_HB, 0, 327680 + 307200, stream);
    gemm_bt<<<dim3(48, 10), 256, 0, stream>>>(ABF, WBF + 2 * WSEG, BIAS + 2 * NG, GF, NG, KP1);
    gemm_bt<<<dim3(48, 10), 256, 0, stream>>>(ABF, WBF + 3 * WSEG, BIAS + 3 * NG, GR, NG, KP1);
    for (int t = 0; t < 48; t++) {
        int ib = t & 1, ob = ib ^ 1;
        lstm_mfma<<<dim3(10, 2), 256, 0, stream>>>(GF, GR, WBF + 6 * WSEG, WBF + 7 * WSEG,
                                                   HF[ib], HR[ib], HF[ob], HR[ob], CFp, CRp, t);
    }

    // ---- pooling + classifier ----
    dctx_k<<<dim3((128 * 600 + 255) / 256), 256, 0, stream>>>(HF[0], HR[0], DCTX);
    pool_k<<<dim3((64 * 2400 + 255) / 256), 256, 0, stream>>>(DCTX, x1m, x2m, POOL);
    fc2_k<<<dim3(75), 256, 0, stream>>>(POOL, f2w, f2b, LOGIT);
    out_k<<<dim3(1), 256, 0, stream>>>(LOGIT, fow, fob, (float*)d_out);
}

// Round 4
// 2729.182 us; speedup vs baseline: 1.9614x; 1.1482x over previous
//
#include <hip/hip_runtime.h>
#include <math.h>

typedef unsigned short u16;
typedef __attribute__((ext_vector_type(8))) __bf16 bf16x8;
typedef __attribute__((ext_vector_type(4))) float f32x4;

// ---------------- problem constants ----------------
#define MR   6144      // 48*128 rows (t-major: row = t*128 + bc)
#define KP1  320       // padded K for E=H=300
#define NPG  1280      // padded gate rows (1200 real, interleaved 4j+g)
#define NG   1200
#define WSEG 409600    // u16 elements per weight segment [1280][320]
#define NBLK 20        // persistent lstm blocks (10 n-tiles x 2 dirs)

// ---------------- workspace layout (byte offsets, 16B aligned) ----------------
#define OFF_ABF    0UL           // bf16 [6144][320]            3,932,160
#define OFF_WBF    3932160UL     // bf16 8 x [1280][320]        6,553,600 (eW,rW,dW,sW,eU,rU,dU,sU)
#define OFF_WCF    10485760UL    // f32  [300][1800] folded fc1 2,160,000
#define OFF_BIAS   12645760UL    // f32  4 x 1200 interleaved      19,200
#define OFF_GF     12664960UL    // f32  [6144][1200]          29,491,200
#define OFF_GR     42156160UL    // f32  [6144][1200]          29,491,200
#define OFF_HB     71647360UL    // bf16 2 bufs x 2 dirs x [128][320]  327,680
#define OFF_ENC    71975040UL    // f32  [128][600]               307,200
#define OFF_VB     72282240UL    // f32  8 x [64][600]          1,228,800
#define OFF_CO     73511040UL    // f32  8 x [64][300]            614,400
#define OFF_ATT    74125440UL    // f32  3 x 48*64 (AMX,AMN,SS)    36,864
#define OFF_PT     74162304UL    // f32  [2400][64] pooled^T      614,400
#define OFF_LG     74776704UL    // f32  64*300                    76,800
#define OFF_BAR    74853504UL    // u32  barrier counters             256

__device__ __forceinline__ float sigf(float x) { return 1.0f / (1.0f + expf(-x)); }

__device__ __forceinline__ u16 f2bf(float x) {
    union { float f; unsigned int u; } v; v.f = x;
    unsigned int r = v.u + 0x7fffu + ((v.u >> 16) & 1u);   // RNE
    return (u16)(r >> 16);
}
__device__ __forceinline__ float bf2f(u16 x) {
    union { unsigned int u; float f; } v; v.u = ((unsigned int)x) << 16; return v.f;
}

__device__ __forceinline__ void gld_lds16(const u16* g, u16* l) {
    __builtin_amdgcn_global_load_lds(
        (const __attribute__((address_space(1))) unsigned int*)g,
        (__attribute__((address_space(3))) unsigned int*)l, 16, 0, 0);
}

// ---------------- embedding gather -> bf16, K zero-padded ----------------
__global__ __launch_bounds__(256) void gather_bf(const int* __restrict__ x1,
                                                 const int* __restrict__ x2,
                                                 const float* __restrict__ emb,
                                                 u16* __restrict__ abf) {
    int idx = blockIdx.x * 256 + threadIdx.x;
    if (idx >= MR * KP1) return;
    int r = idx / KP1, k = idx % KP1;
    float v = 0.0f;
    if (k < 300) {
        int t = r >> 7, bc = r & 127;
        int tok = (bc < 64) ? x1[t * 64 + bc] : x2[t * 64 + bc - 64];
        v = emb[tok * 300 + k];
    }
    abf[idx] = f2bf(v);
}

// ---------------- 8 weight matrices [1200][300] -> gate-interleaved bf16 [1280][320] ----------------
__global__ __launch_bounds__(256) void wconv8_k(const float* __restrict__ w0, const float* __restrict__ w1,
                                                const float* __restrict__ w2, const float* __restrict__ w3,
                                                const float* __restrict__ w4, const float* __restrict__ w5,
                                                const float* __restrict__ w6, const float* __restrict__ w7,
                                                u16* __restrict__ out) {
    int idx = blockIdx.x * 256 + threadIdx.x;
    if (idx >= 8 * NPG * KP1) return;
    int s = idx / (NPG * KP1), rem = idx % (NPG * KP1);
    int r = rem / KP1, k = rem % KP1;
    const float* w = (s == 0) ? w0 : (s == 1) ? w1 : (s == 2) ? w2 : (s == 3) ? w3
                   : (s == 4) ? w4 : (s == 5) ? w5 : (s == 6) ? w6 : w7;
    float v = 0.0f;
    if (r < NG && k < 300) {
        int j = r >> 2, g = r & 3;           // interleaved row 4j+g <- source row g*300+j
        v = w[(g * 300 + j) * 300 + k];
    }
    out[idx] = f2bf(v);
}

// ---------------- 4 bias pairs -> interleaved f32 [4][1200] ----------------
__global__ __launch_bounds__(256) void bconv_k(const float* __restrict__ b0i, const float* __restrict__ b0h,
                                               const float* __restrict__ b1i, const float* __restrict__ b1h,
                                               const float* __restrict__ b2i, const float* __restrict__ b2h,
                                               const float* __restrict__ b3i, const float* __restrict__ b3h,
                                               float* __restrict__ out) {
    int idx = blockIdx.x * 256 + threadIdx.x;
    if (idx >= 4 * NG) return;
    int s = idx / NG, n = idx % NG;
    int j = n >> 2, g = n & 3;
    int src = g * 300 + j;
    const float* bi = (s == 0) ? b0i : (s == 1) ? b1i : (s == 2) ? b2i : b3i;
    const float* bh = (s == 0) ? b0h : (s == 1) ? b1h : (s == 2) ? b2h : b3h;
    out[idx] = bi[src] + bh[src];
}

// ---------------- folded fc1 weight (fp32) [300][1800] ----------------
__global__ __launch_bounds__(256) void wcat_k(const float* __restrict__ f1w,
                                              float* __restrict__ wc) {
    int idx = blockIdx.x * 256 + threadIdx.x;
    if (idx >= 300 * 1800) return;
    int n = idx / 1800, k = idx % 1800;
    int nk = n * 2400 + k;
    float v;
    if (k < 600)       v = f1w[nk] + f1w[nk + 1800];   // c coeff: W1+W4
    else if (k < 1200) v = f1w[nk] - f1w[nk + 1200];   // a coeff: W2-W4
    else               v = f1w[nk];                    // c*a coeff: W3
    wc[idx] = v;
}

// ---------------- bf16 MFMA GEMM: C[M][1200] f32 = A@B^T + bias ----------------
__global__ __launch_bounds__(256) void gemm_bt(const u16* __restrict__ A,
                                               const u16* __restrict__ B,
                                               const float* __restrict__ bias,
                                               float* __restrict__ C,
                                               int N, int Kpad) {
    __shared__ __align__(16) u16 smA[128 * 32];
    __shared__ __align__(16) u16 smB[128 * 32];
    int m0 = blockIdx.x * 128, n0 = blockIdx.y * 128;
    int tid = threadIdx.x, ln = tid & 63;
    int wm = (tid >> 6) & 1, wn = tid >> 7;
    int lrow = ln & 15, lq = ln >> 4;
    f32x4 acc[4][4] = {};
    for (int k0 = 0; k0 < Kpad; k0 += 32) {
#pragma unroll
        for (int p = 0; p < 2; p++) {
            int e = (p * 256 + tid) * 8;
            int r = e >> 5, kk = e & 31;
            gld_lds16(A + (size_t)(m0 + r) * Kpad + k0 + kk, smA + e);
            gld_lds16(B + (size_t)(n0 + r) * Kpad + k0 + kk, smB + e);
        }
        __syncthreads();
        bf16x8 av[4], bv[4];
#pragma unroll
        for (int i = 0; i < 4; i++) {
            av[i] = *(const bf16x8*)&smA[(wm * 64 + i * 16 + lrow) * 32 + lq * 8];
            bv[i] = *(const bf16x8*)&smB[(wn * 64 + i * 16 + lrow) * 32 + lq * 8];
        }
#pragma unroll
        for (int i = 0; i < 4; i++)
#pragma unroll
            for (int j = 0; j < 4; j++)
                acc[i][j] = __builtin_amdgcn_mfma_f32_16x16x32_bf16(av[i], bv[j], acc[i][j], 0, 0, 0);
        __syncthreads();
    }
#pragma unroll
    for (int i = 0; i < 4; i++)
#pragma unroll
        for (int j = 0; j < 4; j++) {
            int n = n0 + wn * 64 + j * 16 + lrow;
            if (n < N) {
                float bb = bias[n];
#pragma unroll
                for (int r = 0; r < 4; r++) {
                    int m = m0 + wm * 64 + i * 16 + lq * 4 + r;
                    C[(size_t)m * N + n] = acc[i][j][r] + bb;
                }
            }
        }
}

// ---------------- persistent MFMA LSTM: all 48 steps, both dirs, grid (10,2) ----------------
// U resident in LDS; h A-fragments direct from global; c in VGPRs; global spin-barrier per step.
__global__ __launch_bounds__(256, 1) void lstm_persist(const float* __restrict__ Gf,
                                                       const float* __restrict__ Gr,
                                                       const u16* __restrict__ Uf,
                                                       const u16* __restrict__ Ur,
                                                       u16* __restrict__ hb,
                                                       unsigned* __restrict__ bar) {
    int dir = blockIdx.y;
    const float* G = dir ? Gr : Gf;
    const u16* U = dir ? Ur : Uf;
    int nt = blockIdx.x;
    int n0 = nt * 128;
    int tid = threadIdx.x, ln = tid & 63;
    int wm = (tid >> 6) & 1, wn = tid >> 7;
    int lrow = ln & 15, lq = ln >> 4;

    __shared__ __align__(16) u16 Ulds[10 * 4096];   // 80 KB: this block's U slice, tiled per-kt
    __shared__ float P[128][128];                   // 64 KB gate staging

    for (int kt = 0; kt < 10; kt++) {
#pragma unroll
        for (int p = 0; p < 2; p++) {
            int e = (p * 256 + tid) * 8;
            int r = e >> 5, kk = e & 31;
            gld_lds16(U + (size_t)(n0 + r) * KP1 + kt * 32 + kk, Ulds + kt * 4096 + e);
        }
    }
    __syncthreads();

    int jl = tid & 31, bg = tid >> 5;
    int jglob = nt * 32 + jl;
    float creg[16];
#pragma unroll
    for (int i = 0; i < 16; i++) creg[i] = 0.0f;

    for (int t = 0; t < 48; t++) {
        int tt = dir ? 47 - t : t;
        const u16* hin = hb + (size_t)(t & 1) * 81920 + (size_t)dir * 40960;
        u16* hout = hb + (size_t)((t + 1) & 1) * 81920 + (size_t)dir * 40960;

        f32x4 acc[4][4] = {};
        for (int kt = 0; kt < 10; kt++) {
            bf16x8 av[4], bv[4];
#pragma unroll
            for (int i = 0; i < 4; i++)
                av[i] = *(const bf16x8*)(hin + (size_t)(wm * 64 + i * 16 + lrow) * KP1 + kt * 32 + lq * 8);
#pragma unroll
            for (int i = 0; i < 4; i++)
                bv[i] = *(const bf16x8*)&Ulds[kt * 4096 + (wn * 64 + i * 16 + lrow) * 32 + lq * 8];
#pragma unroll
            for (int i = 0; i < 4; i++)
#pragma unroll
                for (int j = 0; j < 4; j++)
                    acc[i][j] = __builtin_amdgcn_mfma_f32_16x16x32_bf16(av[i], bv[j], acc[i][j], 0, 0, 0);
        }
#pragma unroll
        for (int i = 0; i < 4; i++)
#pragma unroll
            for (int j = 0; j < 4; j++) {
                int nl = wn * 64 + j * 16 + lrow;
                int n = n0 + nl;
#pragma unroll
                for (int r = 0; r < 4; r++) {
                    int m = wm * 64 + i * 16 + lq * 4 + r;
                    float g = (n < NG) ? G[(size_t)(tt * 128 + m) * NG + n] : 0.0f;
                    P[m][nl] = acc[i][j][r] + g;
                }
            }
        __syncthreads();
        if (jglob < 300) {
#pragma unroll
            for (int bb = 0; bb < 16; bb++) {
                int b = bg * 16 + bb;
                f32x4 gv = *(const f32x4*)&P[b][4 * jl];    // i,f,g,o
                float cn = sigf(gv[1]) * creg[bb] + sigf(gv[0]) * tanhf(gv[2]);
                float hn = sigf(gv[3]) * tanhf(cn);
                creg[bb] = cn;
                hout[(size_t)b * KP1 + jglob] = f2bf(hn);
            }
        }
        if (t < 47) {
            __syncthreads();                 // drain this block's h stores (vmcnt(0)) + P reads done
            if (tid == 0) {
                __threadfence();             // flush to device coherence point (release)
                __hip_atomic_fetch_add(bar, 1u, __ATOMIC_ACQ_REL, __HIP_MEMORY_SCOPE_AGENT);
                unsigned tgt = NBLK * (unsigned)(t + 1);
                while (__hip_atomic_load(bar, __ATOMIC_ACQUIRE, __HIP_MEMORY_SCOPE_AGENT) < tgt)
                    __builtin_amdgcn_s_sleep(8);
            }
            __syncthreads();
            __threadfence();                 // acquire: invalidate caches before reading fresh h
        }
    }
}

// ---------------- final-h concat (batch-reversal quirk): [128][600] f32 ----------------
__global__ __launch_bounds__(256) void enc_k(const u16* __restrict__ hF,
                                             const u16* __restrict__ hR,
                                             float* __restrict__ enc) {
    int idx = blockIdx.x * 256 + threadIdx.x;
    if (idx >= 128 * 600) return;
    int bc = idx / 600, d = idx % 600;
    int seq = bc >> 6, b = bc & 63;
    enc[idx] = (d < 300) ? bf2f(hF[bc * KP1 + d])
                         : bf2f(hR[(seq * 64 + 63 - b) * KP1 + d - 300]);
}

// ---------------- build 8 coefficient vectors V[8][64][600] ----------------
__global__ __launch_bounds__(256) void vbuf_k(const float* __restrict__ enc,
                                              float* __restrict__ V) {
    int idx = blockIdx.x * 256 + threadIdx.x;
    if (idx >= 64 * 600) return;
    int b = idx / 600, d = idx % 600;
    float e1 = enc[b * 600 + d], e2 = enc[(64 + b) * 600 + d];
    float p = fmaxf(e2, 0.0f), nn = fminf(e2, 0.0f);
    V[0 * 38400 + idx] = e1;
    V[1 * 38400 + idx] = p;
    V[2 * 38400 + idx] = nn;
    V[3 * 38400 + idx] = e1 * p;
    V[4 * 38400 + idx] = e1 * nn;
    V[5 * 38400 + idx] = e2;
    V[6 * 38400 + idx] = e1;
    V[7 * 38400 + idx] = e1 * e2;
}

// ---------------- attention scalars (rank-1 collapse): AMX/AMN/SS [48][64] ----------------
__global__ __launch_bounds__(256) void attn_lite(const float* __restrict__ enc,
                                                 const float* __restrict__ x1m,
                                                 const float* __restrict__ x2m,
                                                 float* __restrict__ AMX,
                                                 float* __restrict__ AMN,
                                                 float* __restrict__ SS) {
    int b = blockIdx.x, tid = threadIdx.x;
    __shared__ float sc[48][49];
    __shared__ float rmx[4], rmn[4];
    __shared__ float MxMn[2];
    float mx = -3.4e38f, mn = 3.4e38f;
    for (int d = tid; d < 600; d += 256) {
        float p = enc[b * 600 + d] * enc[(64 + b) * 600 + d];
        mx = fmaxf(mx, p); mn = fminf(mn, p);
    }
    for (int off = 32; off; off >>= 1) {
        mx = fmaxf(mx, __shfl_down(mx, off));
        mn = fminf(mn, __shfl_down(mn, off));
    }
    if ((tid & 63) == 0) { rmx[tid >> 6] = mx; rmn[tid >> 6] = mn; }
    __syncthreads();
    if (tid == 0) {
        MxMn[0] = fmaxf(fmaxf(rmx[0], rmx[1]), fmaxf(rmx[2], rmx[3]));
        MxMn[1] = fminf(fminf(rmn[0], rmn[1]), fminf(rmn[2], rmn[3]));
    }
    __syncthreads();
    float Mx = MxMn[0], Mn = MxMn[1];
    for (int idx = tid; idx < 2304; idx += 256) {
        int i = idx / 48, j = idx % 48;
        float q = x1m[i * 64 + b] * x2m[j * 64 + b];
        sc[i][j] = (q > 0.0f) ? q * Mx : ((q < 0.0f) ? q * Mn : 0.0f);
    }
    __syncthreads();
    if (tid < 48) {                       // alpha over axis j, row i = tid
        int i = tid;
        float m = -3.4e38f;
        for (int j = 0; j < 48; j++) m = fmaxf(m, sc[i][j]);
        float sum = 0.0f;
        for (int j = 0; j < 48; j++) sum += expf(sc[i][j] - m) * x2m[j * 64 + b];
        float wmax = -3.4e38f, wmin = 3.4e38f;
        for (int j = 0; j < 48; j++) {
            float w = expf(sc[i][j] - m) * x2m[j * 64 + b] * x2m[j * 64 + b];
            wmax = fmaxf(wmax, w); wmin = fminf(wmin, w);
        }
        AMX[i * 64 + b] = wmax / sum;
        AMN[i * 64 + b] = wmin / sum;
    } else if (tid >= 64 && tid < 112) {  // beta over axis i, col j = tid-64
        int j = tid - 64;
        float m = -3.4e38f;
        for (int i = 0; i < 48; i++) m = fmaxf(m, sc[i][j]);
        float sum = 0.0f, sm = 0.0f;
        for (int i = 0; i < 48; i++) {
            float e = expf(sc[i][j] - m) * x1m[i * 64 + b];
            sum += e; sm += e * x1m[i * 64 + b];
        }
        SS[j * 64 + b] = sm / sum;
    }
}

// ---------------- 8 small fp32 GEMMs: CO[s][64][300] = V[s] @ WcSlice^T ----------------
__global__ __launch_bounds__(256) void coeff_gemm(const float* __restrict__ V,
                                                  const float* __restrict__ Wc,
                                                  float* __restrict__ CO) {
    __shared__ float As[16][64];
    __shared__ float Ws[16][64];
    int s = blockIdx.y;
    const int offs[8] = {0, 600, 600, 1200, 1200, 0, 600, 1200};
    int koff = offs[s];
    const float* A = V + (size_t)s * 38400;
    float* C = CO + (size_t)s * 19200;
    int n0 = blockIdx.x * 64;
    int tid = threadIdx.x;
    int lrow = tid >> 2;
    int lk4 = (tid & 3) << 2;
    int tm = (tid & 15) << 2;
    int tn = (tid >> 4) << 2;
    int nW = n0 + lrow;
    float acc[4][4] = {};
    for (int k0 = 0; k0 < 600; k0 += 16) {
        __syncthreads();
#pragma unroll
        for (int q = 0; q < 4; q++) {
            int k = k0 + lk4 + q;
            As[lk4 + q][lrow] = (k < 600) ? A[lrow * 600 + k] : 0.0f;
            Ws[lk4 + q][lrow] = (k < 600 && nW < 300) ? Wc[(size_t)nW * 1800 + koff + k] : 0.0f;
        }
        __syncthreads();
#pragma unroll
        for (int kk = 0; kk < 16; kk++) {
            float a0 = As[kk][tm], a1 = As[kk][tm + 1], a2 = As[kk][tm + 2], a3 = As[kk][tm + 3];
            float w0 = Ws[kk][tn], w1 = Ws[kk][tn + 1], w2 = Ws[kk][tn + 2], w3 = Ws[kk][tn + 3];
            acc[0][0] += a0 * w0; acc[0][1] += a0 * w1; acc[0][2] += a0 * w2; acc[0][3] += a0 * w3;
            acc[1][0] += a1 * w0; acc[1][1] += a1 * w1; acc[1][2] += a1 * w2; acc[1][3] += a1 * w3;
            acc[2][0] += a2 * w0; acc[2][1] += a2 * w1; acc[2][2] += a2 * w2; acc[2][3] += a2 * w3;
            acc[3][0] += a3 * w0; acc[3][1] += a3 * w1; acc[3][2] += a3 * w2; acc[3][3] += a3 * w3;
        }
    }
#pragma unroll
    for (int ii = 0; ii < 4; ii++) {
        int m = tm + ii;
#pragma unroll
        for (int jn = 0; jn < 4; jn++) {
            int n = n0 + tn + jn;
            if (n < 300) C[m * 300 + n] = acc[ii][jn];
        }
    }
}

// ---------------- rank-combine + relu -> bf16 h1 (t-major [6144][320]) ----------------
__global__ __launch_bounds__(320) void combine_k(const float* __restrict__ CO,
                                                 const float* __restrict__ f1b,
                                                 const float* __restrict__ x1m,
                                                 const float* __restrict__ x2m,
                                                 const float* __restrict__ AMX,
                                                 const float* __restrict__ AMN,
                                                 const float* __restrict__ SS,
                                                 u16* __restrict__ OUT) {
    int r = blockIdx.x;
    int t = r >> 7, bc = r & 127;
    int seq = bc >> 6, b = bc & 63;
    int n = threadIdx.x;
    if (n >= 300) return;
    int bn = b * 300 + n;
    float pre;
    if (seq == 0) {
        float m1 = x1m[t * 64 + b], am = AMX[t * 64 + b], an = AMN[t * 64 + b];
        pre = m1 * CO[bn] + am * CO[19200 + bn] + an * CO[2 * 19200 + bn]
            + m1 * am * CO[3 * 19200 + bn] + m1 * an * CO[4 * 19200 + bn] + f1b[n];
    } else {
        float m2 = x2m[t * 64 + b], sv = SS[t * 64 + b];
        pre = m2 * CO[5 * 19200 + bn] + sv * CO[6 * 19200 + bn]
            + m2 * sv * CO[7 * 19200 + bn] + f1b[n];
    }
    OUT[(size_t)r * KP1 + n] = f2bf(fmaxf(pre, 0.0f));
}

// ---------------- masked mean/max pooling -> pooled^T [2400][64] ----------------
__global__ __launch_bounds__(256) void pool_k(const float* __restrict__ dctx,
                                              const float* __restrict__ x1m,
                                              const float* __restrict__ x2m,
                                              float* __restrict__ pooledT) {
    int idx = blockIdx.x * 256 + threadIdx.x;
    if (idx >= 64 * 2400) return;
    int b = idx / 2400, col = idx % 2400;
    int sec = col / 600, d = col % 600;
    const float* msk = (sec < 2) ? x1m : x2m;
    float v = dctx[((sec < 2 ? 0 : 64) + b) * 600 + d];
    float out;
    if ((sec & 1) == 0) {
        float s = 0, sm = 0;
        for (int t = 0; t < 48; t++) { float mv = msk[t * 64 + b]; s += v * mv; sm += mv; }
        out = s / sm;
    } else {
        float m = -3.4e38f;
        for (int t = 0; t < 48; t++) m = fmaxf(m, v * msk[t * 64 + b]);
        out = m;
    }
    pooledT[col * 64 + b] = out;
}

// ---------------- fc2 + tanh (k-parallel, coalesced pooled^T) ----------------
__global__ __launch_bounds__(256) void fc2_k2(const float* __restrict__ pooledT,
                                              const float* __restrict__ f2w,
                                              const float* __restrict__ f2b,
                                              float* __restrict__ logit) {
    __shared__ float wl[2400];
    __shared__ float red[256];
    int n = blockIdx.x;
    for (int i = threadIdx.x; i < 2400; i += 256) wl[i] = f2w[n * 2400 + i];
    __syncthreads();
    int b = threadIdx.x & 63, kc = threadIdx.x >> 6;
    float acc = 0.0f;
    int k0 = kc * 600;
    for (int kk = 0; kk < 600; kk++) acc += pooledT[(k0 + kk) * 64 + b] * wl[k0 + kk];
    red[threadIdx.x] = acc;
    __syncthreads();
    if (threadIdx.x < 64) {
        float s = red[b] + red[64 + b] + red[128 + b] + red[192 + b];
        logit[b * 300 + n] = tanhf(s + f2b[n]);
    }
}

// ---------------- output layer (wave-reduced) ----------------
__global__ __launch_bounds__(64) void out_k2(const float* __restrict__ logit,
                                             const float* __restrict__ fow,
                                             const float* __restrict__ fob,
                                             float* __restrict__ out) {
    int b = blockIdx.x, tid = threadIdx.x;
    float p0 = 0, p1 = 0, p2 = 0;
    for (int k = tid; k < 300; k += 64) {
        float l = logit[b * 300 + k];
        p0 += l * fow[k]; p1 += l * fow[300 + k]; p2 += l * fow[600 + k];
    }
    for (int off = 32; off; off >>= 1) {
        p0 += __shfl_down(p0, off);
        p1 += __shfl_down(p1, off);
        p2 += __shfl_down(p2, off);
    }
    if (tid == 0) {
        out[b * 3 + 0] = p0 + fob[0];
        out[b * 3 + 1] = p1 + fob[1];
        out[b * 3 + 2] = p2 + fob[2];
    }
}

extern "C" void kernel_launch(void* const* d_in, const int* in_sizes, int n_in,
                              void* d_out, int out_size, void* d_ws, size_t ws_size,
                              hipStream_t stream) {
    (void)in_sizes; (void)n_in; (void)out_size; (void)ws_size;
    const int*   x1  = (const int*)d_in[0];
    const float* x1m = (const float*)d_in[1];
    const int*   x2  = (const int*)d_in[2];
    const float* x2m = (const float*)d_in[3];
    const float* emb = (const float*)d_in[5];
    const float* eW  = (const float*)d_in[6];
    const float* eU  = (const float*)d_in[7];
    const float* ebi = (const float*)d_in[8];
    const float* ebh = (const float*)d_in[9];
    const float* rW  = (const float*)d_in[10];
    const float* rU  = (const float*)d_in[11];
    const float* rbi = (const float*)d_in[12];
    const float* rbh = (const float*)d_in[13];
    const float* dW  = (const float*)d_in[14];
    const float* dU  = (const float*)d_in[15];
    const float* dbi = (const float*)d_in[16];
    const float* dbh = (const float*)d_in[17];
    const float* sW  = (const float*)d_in[18];
    const float* sU  = (const float*)d_in[19];
    const float* sbi = (const float*)d_in[20];
    const float* sbh = (const float*)d_in[21];
    const float* f1w = (const float*)d_in[22];
    const float* f1b = (const float*)d_in[23];
    const float* f2w = (const float*)d_in[24];
    const float* f2b = (const float*)d_in[25];
    const float* fow = (const float*)d_in[26];
    const float* fob = (const float*)d_in[27];

    char* wsb = (char*)d_ws;
    u16*      ABF  = (u16*)(wsb + OFF_ABF);
    u16*      WBF  = (u16*)(wsb + OFF_WBF);
    float*    WCF  = (float*)(wsb + OFF_WCF);
    float*    BIAS = (float*)(wsb + OFF_BIAS);
    float*    GF   = (float*)(wsb + OFF_GF);
    float*    GR   = (float*)(wsb + OFF_GR);
    u16*      HB   = (u16*)(wsb + OFF_HB);
    float*    ENC  = (float*)(wsb + OFF_ENC);
    float*    VB   = (float*)(wsb + OFF_VB);
    float*    CO   = (float*)(wsb + OFF_CO);
    float*    AMX  = (float*)(wsb + OFF_ATT);
    float*    AMN  = AMX + 3072;
    float*    SS   = AMX + 6144;
    float*    PT   = (float*)(wsb + OFF_PT);
    float*    LG   = (float*)(wsb + OFF_LG);
    unsigned* BAR0 = (unsigned*)(wsb + OFF_BAR);
    unsigned* BAR1 = BAR0 + 4;

    u16* HF0 = HB;
    u16* HR0 = HB + 40960;

    // ---- conversions ----
    gather_bf<<<dim3((MR * KP1 + 255) / 256), 256, 0, stream>>>(x1, x2, emb, ABF);
    wconv8_k<<<dim3((8 * NPG * KP1 + 255) / 256), 256, 0, stream>>>(eW, rW, dW, sW, eU, rU, dU, sU, WBF);
    bconv_k<<<dim3((4 * NG + 255) / 256), 256, 0, stream>>>(ebi, ebh, rbi, rbh, dbi, dbh, sbi, sbh, BIAS);
    wcat_k<<<dim3((300 * 1800 + 255) / 256), 256, 0, stream>>>(f1w, WCF);
    hipMemsetAsync(wsb + OFF_BAR, 0, 256, stream);

    // ---- encoder ----
    hipMemsetAsync(wsb + OFF_HB, 0, 327680, stream);
    gemm_bt<<<dim3(48, 10), 256, 0, stream>>>(ABF, WBF,        BIAS,      GF, NG, KP1);
    gemm_bt<<<dim3(48, 10), 256, 0, stream>>>(ABF, WBF + WSEG, BIAS + NG, GR, NG, KP1);
    lstm_persist<<<dim3(10, 2), 256, 0, stream>>>(GF, GR, WBF + 4 * WSEG, WBF + 5 * WSEG, HB, BAR0);

    // ---- attention (rank-1 collapse) + fc1 ----
    enc_k<<<dim3((128 * 600 + 255) / 256), 256, 0, stream>>>(HF0, HR0, ENC);
    vbuf_k<<<dim3((64 * 600 + 255) / 256), 256, 0, stream>>>(ENC, VB);
    attn_lite<<<dim3(64), 256, 0, stream>>>(ENC, x1m, x2m, AMX, AMN, SS);
    coeff_gemm<<<dim3(5, 8), 256, 0, stream>>>(VB, WCF, CO);
    combine_k<<<dim3(6144), 320, 0, stream>>>(CO, f1b, x1m, x2m, AMX, AMN, SS, ABF);

    // ---- decoder ----
    hipMemsetAsync(wsb + OFF_HB, 0, 327680, stream);
    gemm_bt<<<dim3(48, 10), 256, 0, stream>>>(ABF, WBF + 2 * WSEG, BIAS + 2 * NG, GF, NG, KP1);
    gemm_bt<<<dim3(48, 10), 256, 0, stream>>>(ABF, WBF + 3 * WSEG, BIAS + 3 * NG, GR, NG, KP1);
    lstm_persist<<<dim3(10, 2), 256, 0, stream>>>(GF, GR, WBF + 6 * WSEG, WBF + 7 * WSEG, HB, BAR1);

    // ---- pooling + classifier ----
    enc_k<<<dim3((128 * 600 + 255) / 256), 256, 0, stream>>>(HF0, HR0, ENC);
    pool_k<<<dim3((64 * 2400 + 255) / 256), 256, 0, stream>>>(ENC, x1m, x2m, PT);
    fc2_k2<<<dim3(300), 256, 0, stream>>>(PT, f2w, f2b, LG);
    out_k2<<<dim3(64), 64, 0, stream>>>(LG, fow, fob, (float*)d_out);
}

// Round 5
// 1564.471 us; speedup vs baseline: 3.4217x; 1.7445x over previous
//
#include <hip/hip_runtime.h>
#include <math.h>

typedef unsigned short u16;
typedef __attribute__((ext_vector_type(8))) __bf16 bf16x8;
typedef __attribute__((ext_vector_type(4))) float f32x4;
typedef __attribute__((ext_vector_type(4))) _Float16 f16x4;

// ---------------- problem constants ----------------
#define MR   6144      // 48*128 rows (t-major: row = t*128 + bc)
#define KP1  320       // padded K for E=H=300
#define NPG  1280      // padded gate rows (1200 real, interleaved 4j+g)
#define NG   1200
#define WSEG 409600    // u16 elements per weight segment [1280][320]
#define NBLK 20        // persistent lstm blocks (10 n-tiles x 2 dirs)
// G permuted layout (f16): addr = tt*163840 + nt*16384 + ij*1024 + tid*4   (halves)
#define GT_STRIDE 163840
#define GNT_STRIDE 16384

// ---------------- workspace layout (byte offsets, 16B aligned) ----------------
#define OFF_ABF    0UL           // bf16 [6144][320]            3,932,160
#define OFF_WBF    3932160UL     // bf16 8 x [1280][320]        6,553,600 (eW,rW,dW,sW,eU,rU,dU,sU)
#define OFF_WCF    10485760UL    // f32  [300][1800] folded fc1 2,160,000
#define OFF_BIAS   12645760UL    // f32  4 x 1200 interleaved      19,200
#define OFF_GF     12664960UL    // f16  perm [48][10][16][256][4]  15,728,640
#define OFF_GR     28393600UL    // f16  perm                      15,728,640
#define OFF_HB     44122240UL    // bf16 2 bufs x 2 dirs x [128][320]  327,680
#define OFF_ENC    44449920UL    // f32  [128][600]               307,200
#define OFF_VB     44757120UL    // f32  8 x [64][600]          1,228,800
#define OFF_CO     45985920UL    // f32  8 x [64][300]            614,400
#define OFF_ATT    46600320UL    // f32  3 x 48*64 (AMX,AMN,SS)    36,864
#define OFF_PT     46637184UL    // f32  [2400][64] pooled^T      614,400
#define OFF_LG     47251584UL    // f32  64*300                    76,800
#define OFF_BAR    47328384UL    // u32  barrier counters             256

__device__ __forceinline__ float sigf(float x) { return 1.0f / (1.0f + expf(-x)); }

__device__ __forceinline__ u16 f2bf(float x) {
    union { float f; unsigned int u; } v; v.f = x;
    unsigned int r = v.u + 0x7fffu + ((v.u >> 16) & 1u);   // RNE
    return (u16)(r >> 16);
}
__device__ __forceinline__ float bf2f(u16 x) {
    union { unsigned int u; float f; } v; v.u = ((unsigned int)x) << 16; return v.f;
}

__device__ __forceinline__ void gld_lds16(const u16* g, u16* l) {
    __builtin_amdgcn_global_load_lds(
        (const __attribute__((address_space(1))) unsigned int*)g,
        (__attribute__((address_space(3))) unsigned int*)l, 16, 0, 0);
}

// ---------------- embedding gather -> bf16, K zero-padded ----------------
__global__ __launch_bounds__(256) void gather_bf(const int* __restrict__ x1,
                                                 const int* __restrict__ x2,
                                                 const float* __restrict__ emb,
                                                 u16* __restrict__ abf) {
    int idx = blockIdx.x * 256 + threadIdx.x;
    if (idx >= MR * KP1) return;
    int r = idx / KP1, k = idx % KP1;
    float v = 0.0f;
    if (k < 300) {
        int t = r >> 7, bc = r & 127;
        int tok = (bc < 64) ? x1[t * 64 + bc] : x2[t * 64 + bc - 64];
        v = emb[tok * 300 + k];
    }
    abf[idx] = f2bf(v);
}

// ---------------- 8 weight matrices [1200][300] -> gate-interleaved bf16 [1280][320] ----------------
__global__ __launch_bounds__(256) void wconv8_k(const float* __restrict__ w0, const float* __restrict__ w1,
                                                const float* __restrict__ w2, const float* __restrict__ w3,
                                                const float* __restrict__ w4, const float* __restrict__ w5,
                                                const float* __restrict__ w6, const float* __restrict__ w7,
                                                u16* __restrict__ out) {
    int idx = blockIdx.x * 256 + threadIdx.x;
    if (idx >= 8 * NPG * KP1) return;
    int s = idx / (NPG * KP1), rem = idx % (NPG * KP1);
    int r = rem / KP1, k = rem % KP1;
    const float* w = (s == 0) ? w0 : (s == 1) ? w1 : (s == 2) ? w2 : (s == 3) ? w3
                   : (s == 4) ? w4 : (s == 5) ? w5 : (s == 6) ? w6 : w7;
    float v = 0.0f;
    if (r < NG && k < 300) {
        int j = r >> 2, g = r & 3;           // interleaved row 4j+g <- source row g*300+j
        v = w[(g * 300 + j) * 300 + k];
    }
    out[idx] = f2bf(v);
}

// ---------------- 4 bias pairs -> interleaved f32 [4][1200] ----------------
__global__ __launch_bounds__(256) void bconv_k(const float* __restrict__ b0i, const float* __restrict__ b0h,
                                               const float* __restrict__ b1i, const float* __restrict__ b1h,
                                               const float* __restrict__ b2i, const float* __restrict__ b2h,
                                               const float* __restrict__ b3i, const float* __restrict__ b3h,
                                               float* __restrict__ out) {
    int idx = blockIdx.x * 256 + threadIdx.x;
    if (idx >= 4 * NG) return;
    int s = idx / NG, n = idx % NG;
    int j = n >> 2, g = n & 3;
    int src = g * 300 + j;
    const float* bi = (s == 0) ? b0i : (s == 1) ? b1i : (s == 2) ? b2i : b3i;
    const float* bh = (s == 0) ? b0h : (s == 1) ? b1h : (s == 2) ? b2h : b3h;
    out[idx] = bi[src] + bh[src];
}

// ---------------- folded fc1 weight (fp32) [300][1800] ----------------
__global__ __launch_bounds__(256) void wcat_k(const float* __restrict__ f1w,
                                              float* __restrict__ wc) {
    int idx = blockIdx.x * 256 + threadIdx.x;
    if (idx >= 300 * 1800) return;
    int n = idx / 1800, k = idx % 1800;
    int nk = n * 2400 + k;
    float v;
    if (k < 600)       v = f1w[nk] + f1w[nk + 1800];   // c coeff: W1+W4
    else if (k < 1200) v = f1w[nk] - f1w[nk + 1200];   // a coeff: W2-W4
    else               v = f1w[nk];                    // c*a coeff: W3
    wc[idx] = v;
}

// ---------------- bf16 MFMA GEMM -> G in f16 fragment-major perm layout ----------------
// A [6144][320] bf16, B [1280][320] bf16, grid (48, 10): tile (tt, nt).
// Output fragment (i,j) of thread tid -> Gh[tt*163840 + nt*16384 + (i*4+j)*1024 + tid*4]
__global__ __launch_bounds__(256) void gemm_bt(const u16* __restrict__ A,
                                               const u16* __restrict__ B,
                                               const float* __restrict__ bias,
                                               _Float16* __restrict__ Gh) {
    __shared__ __align__(16) u16 smA[128 * 32];
    __shared__ __align__(16) u16 smB[128 * 32];
    int m0 = blockIdx.x * 128, n0 = blockIdx.y * 128;
    int tid = threadIdx.x, ln = tid & 63;
    int wm = (tid >> 6) & 1, wn = tid >> 7;
    int lrow = ln & 15, lq = ln >> 4;
    f32x4 acc[4][4] = {};
    for (int k0 = 0; k0 < KP1; k0 += 32) {
#pragma unroll
        for (int p = 0; p < 2; p++) {
            int e = (p * 256 + tid) * 8;
            int r = e >> 5, kk = e & 31;
            gld_lds16(A + (size_t)(m0 + r) * KP1 + k0 + kk, smA + e);
            gld_lds16(B + (size_t)(n0 + r) * KP1 + k0 + kk, smB + e);
        }
        __syncthreads();
        bf16x8 av[4], bv[4];
#pragma unroll
        for (int i = 0; i < 4; i++) {
            av[i] = *(const bf16x8*)&smA[(wm * 64 + i * 16 + lrow) * 32 + lq * 8];
            bv[i] = *(const bf16x8*)&smB[(wn * 64 + i * 16 + lrow) * 32 + lq * 8];
        }
#pragma unroll
        for (int i = 0; i < 4; i++)
#pragma unroll
            for (int j = 0; j < 4; j++)
                acc[i][j] = __builtin_amdgcn_mfma_f32_16x16x32_bf16(av[i], bv[j], acc[i][j], 0, 0, 0);
        __syncthreads();
    }
    size_t base = (size_t)(m0 >> 7) * GT_STRIDE + (size_t)(n0 >> 7) * GNT_STRIDE + (size_t)tid * 4;
#pragma unroll
    for (int i = 0; i < 4; i++)
#pragma unroll
        for (int j = 0; j < 4; j++) {
            int n = n0 + wn * 64 + j * 16 + lrow;
            f16x4 v;
            if (n < NG) {
                float bb = bias[n];
#pragma unroll
                for (int r = 0; r < 4; r++) v[r] = (_Float16)(acc[i][j][r] + bb);
            } else {
                v = (f16x4)0;
            }
            *(f16x4*)(Gh + base + (size_t)(i * 4 + j) * 1024) = v;
        }
}

// ---------------- persistent MFMA LSTM: all 48 steps, both dirs, grid (10,2) ----------------
// U resident in LDS; h A-fragments direct from global; c in VGPRs; G prefetched into VGPRs
// in fragment-major f16 layout; global spin-barrier per step.
__global__ __launch_bounds__(256, 1) void lstm_persist(const _Float16* __restrict__ Gf,
                                                       const _Float16* __restrict__ Gr,
                                                       const u16* __restrict__ Uf,
                                                       const u16* __restrict__ Ur,
                                                       u16* __restrict__ hb,
                                                       unsigned* __restrict__ bar) {
    int dir = blockIdx.y;
    const _Float16* G = dir ? Gr : Gf;
    const u16* U = dir ? Ur : Uf;
    int nt = blockIdx.x;
    int n0 = nt * 128;
    int tid = threadIdx.x, ln = tid & 63;
    int wm = (tid >> 6) & 1, wn = tid >> 7;
    int lrow = ln & 15, lq = ln >> 4;

    __shared__ __align__(16) u16 Ulds[10 * 4096];   // 80 KB: this block's U slice, tiled per-kt
    __shared__ float P[128][128];                   // 64 KB gate staging

    for (int kt = 0; kt < 10; kt++) {
#pragma unroll
        for (int p = 0; p < 2; p++) {
            int e = (p * 256 + tid) * 8;
            int r = e >> 5, kk = e & 31;
            gld_lds16(U + (size_t)(n0 + r) * KP1 + kt * 32 + kk, Ulds + kt * 4096 + e);
        }
    }
    __syncthreads();

    int jl = tid & 31, bg = tid >> 5;
    int jglob = nt * 32 + jl;
    float creg[16];
#pragma unroll
    for (int i = 0; i < 16; i++) creg[i] = 0.0f;

    const _Float16* Gbase = G + (size_t)nt * GNT_STRIDE + (size_t)tid * 4;

    // preload G for t = 0
    f16x4 gpre[16];
    {
        int tt0 = dir ? 47 : 0;
        const _Float16* Gt = Gbase + (size_t)tt0 * GT_STRIDE;
#pragma unroll
        for (int ij = 0; ij < 16; ij++)
            gpre[ij] = *(const f16x4*)(Gt + (size_t)ij * 1024);
    }

    for (int t = 0; t < 48; t++) {
        const u16* hin = hb + (size_t)(t & 1) * 81920 + (size_t)dir * 40960;
        u16* hout = hb + (size_t)((t + 1) & 1) * 81920 + (size_t)dir * 40960;

        f32x4 acc[4][4] = {};
        for (int kt = 0; kt < 10; kt++) {
            bf16x8 av[4], bv[4];
#pragma unroll
            for (int i = 0; i < 4; i++)
                av[i] = *(const bf16x8*)(hin + (size_t)(wm * 64 + i * 16 + lrow) * KP1 + kt * 32 + lq * 8);
#pragma unroll
            for (int i = 0; i < 4; i++)
                bv[i] = *(const bf16x8*)&Ulds[kt * 4096 + (wn * 64 + i * 16 + lrow) * 32 + lq * 8];
#pragma unroll
            for (int i = 0; i < 4; i++)
#pragma unroll
                for (int j = 0; j < 4; j++)
                    acc[i][j] = __builtin_amdgcn_mfma_f32_16x16x32_bf16(av[i], bv[j], acc[i][j], 0, 0, 0);
        }
        // stage gate preacts (+G) into LDS
#pragma unroll
        for (int i = 0; i < 4; i++)
#pragma unroll
            for (int j = 0; j < 4; j++) {
                int nl = wn * 64 + j * 16 + lrow;
#pragma unroll
                for (int r = 0; r < 4; r++) {
                    int m = wm * 64 + i * 16 + lq * 4 + r;
                    P[m][nl] = acc[i][j][r] + (float)gpre[i * 4 + j][r];
                }
            }
        __syncthreads();
        // prefetch next step's G (coalesced 8B/lane); drained by the pre-barrier syncthreads
        if (t < 47) {
            int ttn = dir ? 47 - (t + 1) : (t + 1);
            const _Float16* Gt = Gbase + (size_t)ttn * GT_STRIDE;
#pragma unroll
            for (int ij = 0; ij < 16; ij++)
                gpre[ij] = *(const f16x4*)(Gt + (size_t)ij * 1024);
        }
        // gate nonlinearity: thread (jl, bg) handles 16 batch rows of dim jglob
        if (jglob < 300) {
#pragma unroll
            for (int bb = 0; bb < 16; bb++) {
                int b = bg * 16 + bb;
                f32x4 gv = *(const f32x4*)&P[b][4 * jl];    // i,f,g,o
                float cn = sigf(gv[1]) * creg[bb] + sigf(gv[0]) * tanhf(gv[2]);
                float hn = sigf(gv[3]) * tanhf(cn);
                creg[bb] = cn;
                hout[(size_t)b * KP1 + jglob] = f2bf(hn);
            }
        }
        if (t < 47) {
            __syncthreads();                 // drain h stores + G prefetch (vmcnt(0))
            if (tid == 0) {
                __threadfence();             // release
                __hip_atomic_fetch_add(bar, 1u, __ATOMIC_ACQ_REL, __HIP_MEMORY_SCOPE_AGENT);
                unsigned tgt = NBLK * (unsigned)(t + 1);
                while (__hip_atomic_load(bar, __ATOMIC_ACQUIRE, __HIP_MEMORY_SCOPE_AGENT) < tgt)
                    __builtin_amdgcn_s_sleep(8);
            }
            __syncthreads();
            __threadfence();                 // acquire
        }
    }
}

// ---------------- final-h concat (batch-reversal quirk): [128][600] f32 ----------------
__global__ __launch_bounds__(256) void enc_k(const u16* __restrict__ hF,
                                             const u16* __restrict__ hR,
                                             float* __restrict__ enc) {
    int idx = blockIdx.x * 256 + threadIdx.x;
    if (idx >= 128 * 600) return;
    int bc = idx / 600, d = idx % 600;
    int seq = bc >> 6, b = bc & 63;
    enc[idx] = (d < 300) ? bf2f(hF[bc * KP1 + d])
                         : bf2f(hR[(seq * 64 + 63 - b) * KP1 + d - 300]);
}

// ---------------- build 8 coefficient vectors V[8][64][600] ----------------
__global__ __launch_bounds__(256) void vbuf_k(const float* __restrict__ enc,
                                              float* __restrict__ V) {
    int idx = blockIdx.x * 256 + threadIdx.x;
    if (idx >= 64 * 600) return;
    int b = idx / 600, d = idx % 600;
    float e1 = enc[b * 600 + d], e2 = enc[(64 + b) * 600 + d];
    float p = fmaxf(e2, 0.0f), nn = fminf(e2, 0.0f);
    V[0 * 38400 + idx] = e1;
    V[1 * 38400 + idx] = p;
    V[2 * 38400 + idx] = nn;
    V[3 * 38400 + idx] = e1 * p;
    V[4 * 38400 + idx] = e1 * nn;
    V[5 * 38400 + idx] = e2;
    V[6 * 38400 + idx] = e1;
    V[7 * 38400 + idx] = e1 * e2;
}

// ---------------- attention scalars (rank-1 collapse): AMX/AMN/SS [48][64] ----------------
__global__ __launch_bounds__(256) void attn_lite(const float* __restrict__ enc,
                                                 const float* __restrict__ x1m,
                                                 const float* __restrict__ x2m,
                                                 float* __restrict__ AMX,
                                                 float* __restrict__ AMN,
                                                 float* __restrict__ SS) {
    int b = blockIdx.x, tid = threadIdx.x;
    __shared__ float sc[48][49];
    __shared__ float rmx[4], rmn[4];
    __shared__ float MxMn[2];
    float mx = -3.4e38f, mn = 3.4e38f;
    for (int d = tid; d < 600; d += 256) {
        float p = enc[b * 600 + d] * enc[(64 + b) * 600 + d];
        mx = fmaxf(mx, p); mn = fminf(mn, p);
    }
    for (int off = 32; off; off >>= 1) {
        mx = fmaxf(mx, __shfl_down(mx, off));
        mn = fminf(mn, __shfl_down(mn, off));
    }
    if ((tid & 63) == 0) { rmx[tid >> 6] = mx; rmn[tid >> 6] = mn; }
    __syncthreads();
    if (tid == 0) {
        MxMn[0] = fmaxf(fmaxf(rmx[0], rmx[1]), fmaxf(rmx[2], rmx[3]));
        MxMn[1] = fminf(fminf(rmn[0], rmn[1]), fminf(rmn[2], rmn[3]));
    }
    __syncthreads();
    float Mx = MxMn[0], Mn = MxMn[1];
    for (int idx = tid; idx < 2304; idx += 256) {
        int i = idx / 48, j = idx % 48;
        float q = x1m[i * 64 + b] * x2m[j * 64 + b];
        sc[i][j] = (q > 0.0f) ? q * Mx : ((q < 0.0f) ? q * Mn : 0.0f);
    }
    __syncthreads();
    if (tid < 48) {                       // alpha over axis j, row i = tid
        int i = tid;
        float m = -3.4e38f;
        for (int j = 0; j < 48; j++) m = fmaxf(m, sc[i][j]);
        float sum = 0.0f;
        for (int j = 0; j < 48; j++) sum += expf(sc[i][j] - m) * x2m[j * 64 + b];
        float wmax = -3.4e38f, wmin = 3.4e38f;
        for (int j = 0; j < 48; j++) {
            float w = expf(sc[i][j] - m) * x2m[j * 64 + b] * x2m[j * 64 + b];
            wmax = fmaxf(wmax, w); wmin = fminf(wmin, w);
        }
        AMX[i * 64 + b] = wmax / sum;
        AMN[i * 64 + b] = wmin / sum;
    } else if (tid >= 64 && tid < 112) {  // beta over axis i, col j = tid-64
        int j = tid - 64;
        float m = -3.4e38f;
        for (int i = 0; i < 48; i++) m = fmaxf(m, sc[i][j]);
        float sum = 0.0f, sm = 0.0f;
        for (int i = 0; i < 48; i++) {
            float e = expf(sc[i][j] - m) * x1m[i * 64 + b];
            sum += e; sm += e * x1m[i * 64 + b];
        }
        SS[j * 64 + b] = sm / sum;
    }
}

// ---------------- 8 small fp32 GEMMs: CO[s][64][300] = V[s] @ WcSlice^T ----------------
__global__ __launch_bounds__(256) void coeff_gemm(const float* __restrict__ V,
                                                  const float* __restrict__ Wc,
                                                  float* __restrict__ CO) {
    __shared__ float As[16][64];
    __shared__ float Ws[16][64];
    int s = blockIdx.y;
    const int offs[8] = {0, 600, 600, 1200, 1200, 0, 600, 1200};
    int koff = offs[s];
    const float* A = V + (size_t)s * 38400;
    float* C = CO + (size_t)s * 19200;
    int n0 = blockIdx.x * 64;
    int tid = threadIdx.x;
    int lrow = tid >> 2;
    int lk4 = (tid & 3) << 2;
    int tm = (tid & 15) << 2;
    int tn = (tid >> 4) << 2;
    int nW = n0 + lrow;
    float acc[4][4] = {};
    for (int k0 = 0; k0 < 600; k0 += 16) {
        __syncthreads();
#pragma unroll
        for (int q = 0; q < 4; q++) {
            int k = k0 + lk4 + q;
            As[lk4 + q][lrow] = (k < 600) ? A[lrow * 600 + k] : 0.0f;
            Ws[lk4 + q][lrow] = (k < 600 && nW < 300) ? Wc[(size_t)nW * 1800 + koff + k] : 0.0f;
        }
        __syncthreads();
#pragma unroll
        for (int kk = 0; kk < 16; kk++) {
            float a0 = As[kk][tm], a1 = As[kk][tm + 1], a2 = As[kk][tm + 2], a3 = As[kk][tm + 3];
            float w0 = Ws[kk][tn], w1 = Ws[kk][tn + 1], w2 = Ws[kk][tn + 2], w3 = Ws[kk][tn + 3];
            acc[0][0] += a0 * w0; acc[0][1] += a0 * w1; acc[0][2] += a0 * w2; acc[0][3] += a0 * w3;
            acc[1][0] += a1 * w0; acc[1][1] += a1 * w1; acc[1][2] += a1 * w2; acc[1][3] += a1 * w3;
            acc[2][0] += a2 * w0; acc[2][1] += a2 * w1; acc[2][2] += a2 * w2; acc[2][3] += a2 * w3;
            acc[3][0] += a3 * w0; acc[3][1] += a3 * w1; acc[3][2] += a3 * w2; acc[3][3] += a3 * w3;
        }
    }
#pragma unroll
    for (int ii = 0; ii < 4; ii++) {
        int m = tm + ii;
#pragma unroll
        for (int jn = 0; jn < 4; jn++) {
            int n = n0 + tn + jn;
            if (n < 300) C[m * 300 + n] = acc[ii][jn];
        }
    }
}

// ---------------- rank-combine + relu -> bf16 h1 (t-major [6144][320]) ----------------
__global__ __launch_bounds__(320) void combine_k(const float* __restrict__ CO,
                                                 const float* __restrict__ f1b,
                                                 const float* __restrict__ x1m,
                                                 const float* __restrict__ x2m,
                                                 const float* __restrict__ AMX,
                                                 const float* __restrict__ AMN,
                                                 const float* __restrict__ SS,
                                                 u16* __restrict__ OUT) {
    int r = blockIdx.x;
    int t = r >> 7, bc = r & 127;
    int seq = bc >> 6, b = bc & 63;
    int n = threadIdx.x;
    if (n >= 300) return;
    int bn = b * 300 + n;
    float pre;
    if (seq == 0) {
        float m1 = x1m[t * 64 + b], am = AMX[t * 64 + b], an = AMN[t * 64 + b];
        pre = m1 * CO[bn] + am * CO[19200 + bn] + an * CO[2 * 19200 + bn]
            + m1 * am * CO[3 * 19200 + bn] + m1 * an * CO[4 * 19200 + bn] + f1b[n];
    } else {
        float m2 = x2m[t * 64 + b], sv = SS[t * 64 + b];
        pre = m2 * CO[5 * 19200 + bn] + sv * CO[6 * 19200 + bn]
            + m2 * sv * CO[7 * 19200 + bn] + f1b[n];
    }
    OUT[(size_t)r * KP1 + n] = f2bf(fmaxf(pre, 0.0f));
}

// ---------------- masked mean/max pooling -> pooled^T [2400][64] ----------------
__global__ __launch_bounds__(256) void pool_k(const float* __restrict__ dctx,
                                              const float* __restrict__ x1m,
                                              const float* __restrict__ x2m,
                                              float* __restrict__ pooledT) {
    int idx = blockIdx.x * 256 + threadIdx.x;
    if (idx >= 64 * 2400) return;
    int b = idx / 2400, col = idx % 2400;
    int sec = col / 600, d = col % 600;
    const float* msk = (sec < 2) ? x1m : x2m;
    float v = dctx[((sec < 2 ? 0 : 64) + b) * 600 + d];
    float out;
    if ((sec & 1) == 0) {
        float s = 0, sm = 0;
        for (int t = 0; t < 48; t++) { float mv = msk[t * 64 + b]; s += v * mv; sm += mv; }
        out = s / sm;
    } else {
        float m = -3.4e38f;
        for (int t = 0; t < 48; t++) m = fmaxf(m, v * msk[t * 64 + b]);
        out = m;
    }
    pooledT[col * 64 + b] = out;
}

// ---------------- fc2 + tanh (k-parallel, coalesced pooled^T) ----------------
__global__ __launch_bounds__(256) void fc2_k2(const float* __restrict__ pooledT,
                                              const float* __restrict__ f2w,
                                              const float* __restrict__ f2b,
                                              float* __restrict__ logit) {
    __shared__ float wl[2400];
    __shared__ float red[256];
    int n = blockIdx.x;
    for (int i = threadIdx.x; i < 2400; i += 256) wl[i] = f2w[n * 2400 + i];
    __syncthreads();
    int b = threadIdx.x & 63, kc = threadIdx.x >> 6;
    float acc = 0.0f;
    int k0 = kc * 600;
    for (int kk = 0; kk < 600; kk++) acc += pooledT[(k0 + kk) * 64 + b] * wl[k0 + kk];
    red[threadIdx.x] = acc;
    __syncthreads();
    if (threadIdx.x < 64) {
        float s = red[b] + red[64 + b] + red[128 + b] + red[192 + b];
        logit[b * 300 + n] = tanhf(s + f2b[n]);
    }
}

// ---------------- output layer (wave-reduced) ----------------
__global__ __launch_bounds__(64) void out_k2(const float* __restrict__ logit,
                                             const float* __restrict__ fow,
                                             const float* __restrict__ fob,
                                             float* __restrict__ out) {
    int b = blockIdx.x, tid = threadIdx.x;
    float p0 = 0, p1 = 0, p2 = 0;
    for (int k = tid; k < 300; k += 64) {
        float l = logit[b * 300 + k];
        p0 += l * fow[k]; p1 += l * fow[300 + k]; p2 += l * fow[600 + k];
    }
    for (int off = 32; off; off >>= 1) {
        p0 += __shfl_down(p0, off);
        p1 += __shfl_down(p1, off);
        p2 += __shfl_down(p2, off);
    }
    if (tid == 0) {
        out[b * 3 + 0] = p0 + fob[0];
        out[b * 3 + 1] = p1 + fob[1];
        out[b * 3 + 2] = p2 + fob[2];
    }
}

extern "C" void kernel_launch(void* const* d_in, const int* in_sizes, int n_in,
                              void* d_out, int out_size, void* d_ws, size_t ws_size,
                              hipStream_t stream) {
    (void)in_sizes; (void)n_in; (void)out_size; (void)ws_size;
    const int*   x1  = (const int*)d_in[0];
    const float* x1m = (const float*)d_in[1];
    const int*   x2  = (const int*)d_in[2];
    const float* x2m = (const float*)d_in[3];
    const float* emb = (const float*)d_in[5];
    const float* eW  = (const float*)d_in[6];
    const float* eU  = (const float*)d_in[7];
    const float* ebi = (const float*)d_in[8];
    const float* ebh = (const float*)d_in[9];
    const float* rW  = (const float*)d_in[10];
    const float* rU  = (const float*)d_in[11];
    const float* rbi = (const float*)d_in[12];
    const float* rbh = (const float*)d_in[13];
    const float* dW  = (const float*)d_in[14];
    const float* dU  = (const float*)d_in[15];
    const float* dbi = (const float*)d_in[16];
    const float* dbh = (const float*)d_in[17];
    const float* sW  = (const float*)d_in[18];
    const float* sU  = (const float*)d_in[19];
    const float* sbi = (const float*)d_in[20];
    const float* sbh = (const float*)d_in[21];
    const float* f1w = (const float*)d_in[22];
    const float* f1b = (const float*)d_in[23];
    const float* f2w = (const float*)d_in[24];
    const float* f2b = (const float*)d_in[25];
    const float* fow = (const float*)d_in[26];
    const float* fob = (const float*)d_in[27];

    char* wsb = (char*)d_ws;
    u16*       ABF  = (u16*)(wsb + OFF_ABF);
    u16*       WBF  = (u16*)(wsb + OFF_WBF);
    float*     WCF  = (float*)(wsb + OFF_WCF);
    float*     BIAS = (float*)(wsb + OFF_BIAS);
    _Float16*  GFh  = (_Float16*)(wsb + OFF_GF);
    _Float16*  GRh  = (_Float16*)(wsb + OFF_GR);
    u16*       HB   = (u16*)(wsb + OFF_HB);
    float*     ENC  = (float*)(wsb + OFF_ENC);
    float*     VB   = (float*)(wsb + OFF_VB);
    float*     CO   = (float*)(wsb + OFF_CO);
    float*     AMX  = (float*)(wsb + OFF_ATT);
    float*     AMN  = AMX + 3072;
    float*     SS   = AMX + 6144;
    float*     PT   = (float*)(wsb + OFF_PT);
    float*     LG   = (float*)(wsb + OFF_LG);
    unsigned*  BAR0 = (unsigned*)(wsb + OFF_BAR);
    unsigned*  BAR1 = BAR0 + 4;

    u16* HF0 = HB;
    u16* HR0 = HB + 40960;

    // ---- conversions ----
    gather_bf<<<dim3((MR * KP1 + 255) / 256), 256, 0, stream>>>(x1, x2, emb, ABF);
    wconv8_k<<<dim3((8 * NPG * KP1 + 255) / 256), 256, 0, stream>>>(eW, rW, dW, sW, eU, rU, dU, sU, WBF);
    bconv_k<<<dim3((4 * NG + 255) / 256), 256, 0, stream>>>(ebi, ebh, rbi, rbh, dbi, dbh, sbi, sbh, BIAS);
    wcat_k<<<dim3((300 * 1800 + 255) / 256), 256, 0, stream>>>(f1w, WCF);
    hipMemsetAsync(wsb + OFF_BAR, 0, 256, stream);

    // ---- encoder ----
    hipMemsetAsync(wsb + OFF_HB, 0, 327680, stream);
    gemm_bt<<<dim3(48, 10), 256, 0, stream>>>(ABF, WBF,        BIAS,      GFh);
    gemm_bt<<<dim3(48, 10), 256, 0, stream>>>(ABF, WBF + WSEG, BIAS + NG, GRh);
    lstm_persist<<<dim3(10, 2), 256, 0, stream>>>(GFh, GRh, WBF + 4 * WSEG, WBF + 5 * WSEG, HB, BAR0);

    // ---- attention (rank-1 collapse) + fc1 ----
    enc_k<<<dim3((128 * 600 + 255) / 256), 256, 0, stream>>>(HF0, HR0, ENC);
    vbuf_k<<<dim3((64 * 600 + 255) / 256), 256, 0, stream>>>(ENC, VB);
    attn_lite<<<dim3(64), 256, 0, stream>>>(ENC, x1m, x2m, AMX, AMN, SS);
    coeff_gemm<<<dim3(5, 8), 256, 0, stream>>>(VB, WCF, CO);
    combine_k<<<dim3(6144), 320, 0, stream>>>(CO, f1b, x1m, x2m, AMX, AMN, SS, ABF);

    // ---- decoder ----
    hipMemsetAsync(wsb + OFF_HB, 0, 327680, stream);
    gemm_bt<<<dim3(48, 10), 256, 0, stream>>>(ABF, WBF + 2 * WSEG, BIAS + 2 * NG, GFh);
    gemm_bt<<<dim3(48, 10), 256, 0, stream>>>(ABF, WBF + 3 * WSEG, BIAS + 3 * NG, GRh);
    lstm_persist<<<dim3(10, 2), 256, 0, stream>>>(GFh, GRh, WBF + 6 * WSEG, WBF + 7 * WSEG, HB, BAR1);

    // ---- pooling + classifier ----
    enc_k<<<dim3((128 * 600 + 255) / 256), 256, 0, stream>>>(HF0, HR0, ENC);
    pool_k<<<dim3((64 * 2400 + 255) / 256), 256, 0, stream>>>(ENC, x1m, x2m, PT);
    fc2_k2<<<dim3(300), 256, 0, stream>>>(PT, f2w, f2b, LG);
    out_k2<<<dim3(64), 64, 0, stream>>>(LG, fow, fob, (float*)d_out);
}